// Round 1
// baseline (1991.606 us; speedup 1.0000x reference)
//
#include <hip/hip_runtime.h>
#include <hip/hip_bf16.h>

#define T_TOK 1024
#define H_DIM 2048
#define NH 16
#define NKV 4
#define HD 128
#define NEXP 8
#define TOPK 2
#define I_DIM 768
#define EPSF 1e-6f

// ---------------- fused residual add + RMSNorm ----------------
__global__ __launch_bounds__(256) void add_rms(const float* __restrict__ a,
                                               const float* __restrict__ b,
                                               const float* __restrict__ w,
                                               float* __restrict__ res,
                                               float* __restrict__ h) {
    int t = blockIdx.x, tid = threadIdx.x;
    float v[8];
    float ss = 0.f;
#pragma unroll
    for (int i = 0; i < 8; i++) {
        int idx = t * H_DIM + tid + i * 256;
        v[i] = a[idx] + b[idx];
        res[idx] = v[i];
        ss += v[i] * v[i];
    }
#pragma unroll
    for (int o = 32; o; o >>= 1) ss += __shfl_down(ss, o);
    __shared__ float red[4];
    if ((tid & 63) == 0) red[tid >> 6] = ss;
    __syncthreads();
    float tot = red[0] + red[1] + red[2] + red[3];
    float scale = rsqrtf(tot / (float)H_DIM + EPSF);
#pragma unroll
    for (int i = 0; i < 8; i++) {
        int c = tid + i * 256;
        h[t * H_DIM + c] = v[i] * scale * w[c];
    }
}

// ---------------- generic tiled f32 GEMM: C[M,N] = A[M,K] @ B[K,N] ----------------
#define GBM 64
#define GBN 64
#define GBK 16
__global__ __launch_bounds__(256) void gemm_f32(const float* __restrict__ A,
                                                const float* __restrict__ B,
                                                float* __restrict__ C,
                                                int M, int N, int Kd) {
    __shared__ float As[GBK][GBM + 1];
    __shared__ float Bs[GBK][GBN];
    int tid = threadIdx.x;
    int m0 = blockIdx.y * GBM, n0 = blockIdx.x * GBN;
    int tx = tid % 16, ty = tid / 16;
    float acc[4][4] = {};
    for (int k0 = 0; k0 < Kd; k0 += GBK) {
#pragma unroll
        for (int i = 0; i < 4; i++) {
            int e = tid + i * 256;
            int k = e % GBK, m = e / GBK;
            As[k][m] = A[(size_t)(m0 + m) * Kd + k0 + k];
        }
#pragma unroll
        for (int i = 0; i < 4; i++) {
            int e = tid + i * 256;
            int n = e % GBN, k = e / GBN;
            Bs[k][n] = B[(size_t)(k0 + k) * N + n0 + n];
        }
        __syncthreads();
#pragma unroll
        for (int k = 0; k < GBK; k++) {
            float av[4], bv[4];
#pragma unroll
            for (int i = 0; i < 4; i++) av[i] = As[k][ty * 4 + i];
#pragma unroll
            for (int j = 0; j < 4; j++) bv[j] = Bs[k][tx * 4 + j];
#pragma unroll
            for (int i = 0; i < 4; i++)
#pragma unroll
                for (int j = 0; j < 4; j++) acc[i][j] += av[i] * bv[j];
        }
        __syncthreads();
    }
#pragma unroll
    for (int i = 0; i < 4; i++)
#pragma unroll
        for (int j = 0; j < 4; j++)
            C[(size_t)(m0 + ty * 4 + i) * N + n0 + tx * 4 + j] = acc[i][j];
}

// ---------------- QK RMSNorm + neox RoPE (in-place on qkv) ----------------
__global__ __launch_bounds__(128) void qk_rope(float* __restrict__ qkv,
                                               const float* __restrict__ qw,
                                               const float* __restrict__ kw,
                                               const int* __restrict__ positions) {
    int t = blockIdx.x / (NH + NKV);
    int hh = blockIdx.x % (NH + NKV);
    float* x;
    const float* w;
    if (hh < NH) { x = qkv + (size_t)t * 3072 + hh * HD; w = qw; }
    else         { x = qkv + (size_t)t * 3072 + 2048 + (hh - NH) * HD; w = kw; }
    int tid = threadIdx.x;
    float v = x[tid];
    float ss = v * v;
#pragma unroll
    for (int o = 32; o; o >>= 1) ss += __shfl_down(ss, o);
    __shared__ float red[2];
    if ((tid & 63) == 0) red[tid >> 6] = ss;
    __syncthreads();
    float tot = red[0] + red[1];
    float scale = rsqrtf(tot / (float)HD + EPSF);
    float xn = v * scale * w[tid];
    __shared__ float buf[HD];
    buf[tid] = xn;
    __syncthreads();
    if (tid < 64) {
        float x1 = buf[tid], x2 = buf[tid + 64];
        float invf = expf(-((float)tid / 64.0f) * logf(1000000.0f));
        float ang = (float)positions[t] * invf;
        float c = cosf(ang), s = sinf(ang);
        x[tid] = x1 * c - x2 * s;
        x[tid + 64] = x2 * c + x1 * s;
    }
}

// ---------------- flash-style causal GQA attention: one wave per (head, token) ----------------
__global__ __launch_bounds__(256) void attn(const float* __restrict__ qkv,
                                            float* __restrict__ o) {
    int w = blockIdx.x * 4 + (threadIdx.x >> 6);
    int lane = threadIdx.x & 63;
    int t = w % T_TOK;
    int h = w / T_TOK;
    const float* qp = qkv + (size_t)t * 3072 + h * HD;
    int g = h >> 2;  // NH/NKV = 4
    const float* kbase = qkv + 2048 + g * HD;
    const float* vbase = qkv + 2560 + g * HD;
    float2 qv = *(const float2*)(qp + 2 * lane);
    float m = -1e30f, l = 0.f;
    float2 acc = make_float2(0.f, 0.f);
    for (int j = 0; j <= t; j++) {
        float2 kv = *(const float2*)(kbase + (size_t)j * 3072 + 2 * lane);
        float s = qv.x * kv.x + qv.y * kv.y;
        s += __shfl_xor(s, 1); s += __shfl_xor(s, 2); s += __shfl_xor(s, 4);
        s += __shfl_xor(s, 8); s += __shfl_xor(s, 16); s += __shfl_xor(s, 32);
        s *= 0.08838834764831845f;  // 1/sqrt(128)
        float mn = fmaxf(m, s);
        float corr = __expf(m - mn);
        float p = __expf(s - mn);
        l = l * corr + p;
        float2 vv = *(const float2*)(vbase + (size_t)j * 3072 + 2 * lane);
        acc.x = acc.x * corr + p * vv.x;
        acc.y = acc.y * corr + p * vv.y;
        m = mn;
    }
    float inv = 1.f / l;
    float2 r = make_float2(acc.x * inv, acc.y * inv);
    *(float2*)(o + (size_t)t * 2048 + h * HD + 2 * lane) = r;
}

// ---------------- router: softmax over 8 experts, top-2, bucket by expert ----------------
__global__ __launch_bounds__(256) void router(const float* __restrict__ h2,
                                              const float* __restrict__ gate_w,
                                              int* __restrict__ cnt,
                                              int* __restrict__ btok,
                                              int* __restrict__ bslot,
                                              float* __restrict__ bwt) {
    int t = blockIdx.x, tid = threadIdx.x;
    int e = tid & 7, c = tid >> 3;  // c in 0..31
    float part = 0.f;
    for (int i = 0; i < 64; i++) {
        int hh = c * 64 + i;
        part += h2[(size_t)t * H_DIM + hh] * gate_w[hh * NEXP + e];
    }
    __shared__ float red[256];
    red[tid] = part;
    __syncthreads();
    for (int s = 128; s >= 8; s >>= 1) {
        if (tid < s) red[tid] += red[tid + s];
        __syncthreads();
    }
    if (tid == 0) {
        float mx = -1e30f;
        for (int i = 0; i < NEXP; i++) mx = fmaxf(mx, red[i]);
        float p[NEXP];
        for (int i = 0; i < NEXP; i++) p[i] = expf(red[i] - mx);
        int i1 = 0;
        for (int i = 1; i < NEXP; i++) if (p[i] > p[i1]) i1 = i;
        int i2 = (i1 == 0) ? 1 : 0;
        for (int i = 0; i < NEXP; i++) if (i != i1 && p[i] > p[i2]) i2 = i;
        float denom = p[i1] + p[i2];
        float w1 = p[i1] / denom, w2 = p[i2] / denom;
        int pos = atomicAdd(&cnt[i1], 1);
        btok[i1 * T_TOK + pos] = t; bslot[i1 * T_TOK + pos] = t * 2; bwt[i1 * T_TOK + pos] = w1;
        pos = atomicAdd(&cnt[i2], 1);
        btok[i2 * T_TOK + pos] = t; bslot[i2 * T_TOK + pos] = t * 2 + 1; bwt[i2 * T_TOK + pos] = w2;
    }
}

// ---------------- grouped gate_up GEMM + SwiGLU: act[slot] = silu(h2@Wg) * (h2@Wu) ----------------
#define AM 32
#define AN 32
#define AK 32
__global__ __launch_bounds__(256) void moe_gate_up(const float* __restrict__ h2,
                                                   const float* __restrict__ w_gu,
                                                   const int* __restrict__ cnt,
                                                   const int* __restrict__ btok,
                                                   const int* __restrict__ bslot,
                                                   float* __restrict__ act) {
    int e = blockIdx.z;
    int nt = cnt[e];
    int mt0 = blockIdx.y * AM;
    if (mt0 >= nt) return;
    int n0 = blockIdx.x * AN;
    const float* B = w_gu + (size_t)e * H_DIM * (2 * I_DIM);
    __shared__ float As[AK][AM + 1];
    __shared__ float Bg[AK][AN];
    __shared__ float Bu[AK][AN];
    __shared__ int toks[AM];
    int tid = threadIdx.x;
    if (tid < AM) {
        int idx = mt0 + tid;
        toks[tid] = (idx < nt) ? btok[e * T_TOK + idx] : -1;
    }
    __syncthreads();
    int tx = tid % 16, ty = tid / 16;
    float accg[2][2] = {}, accu[2][2] = {};
    for (int k0 = 0; k0 < H_DIM; k0 += AK) {
#pragma unroll
        for (int i = 0; i < 4; i++) {
            int el = tid + i * 256;
            int k = el % AK, mm = el / AK;
            int tk = toks[mm];
            As[k][mm] = (tk >= 0) ? h2[(size_t)tk * H_DIM + k0 + k] : 0.f;
        }
#pragma unroll
        for (int i = 0; i < 4; i++) {
            int el = tid + i * 256;
            int n = el % AN, k = el / AN;
            const float* row = B + (size_t)(k0 + k) * (2 * I_DIM);
            Bg[k][n] = row[n0 + n];
            Bu[k][n] = row[I_DIM + n0 + n];
        }
        __syncthreads();
#pragma unroll
        for (int k = 0; k < AK; k++) {
            float a0 = As[k][ty * 2], a1 = As[k][ty * 2 + 1];
            float g0 = Bg[k][tx * 2], g1 = Bg[k][tx * 2 + 1];
            float u0 = Bu[k][tx * 2], u1 = Bu[k][tx * 2 + 1];
            accg[0][0] += a0 * g0; accg[0][1] += a0 * g1;
            accg[1][0] += a1 * g0; accg[1][1] += a1 * g1;
            accu[0][0] += a0 * u0; accu[0][1] += a0 * u1;
            accu[1][0] += a1 * u0; accu[1][1] += a1 * u1;
        }
        __syncthreads();
    }
#pragma unroll
    for (int i = 0; i < 2; i++) {
        int mm = ty * 2 + i;
        if (mt0 + mm < nt) {
            int slot = bslot[e * T_TOK + mt0 + mm];
#pragma unroll
            for (int j = 0; j < 2; j++) {
                float g = accg[i][j], u = accu[i][j];
                float sg = g / (1.f + expf(-g));
                act[(size_t)slot * I_DIM + n0 + tx * 2 + j] = sg * u;
            }
        }
    }
}

// ---------------- grouped down GEMM + weighted scatter-add ----------------
#define DM 32
#define DN 64
#define DK 32
__global__ __launch_bounds__(256) void moe_down(const float* __restrict__ act,
                                                const float* __restrict__ w_down,
                                                const int* __restrict__ cnt,
                                                const int* __restrict__ btok,
                                                const int* __restrict__ bslot,
                                                const float* __restrict__ bwt,
                                                float* __restrict__ out) {
    int e = blockIdx.z;
    int nt = cnt[e];
    int mt0 = blockIdx.y * DM;
    if (mt0 >= nt) return;
    int n0 = blockIdx.x * DN;
    const float* B = w_down + (size_t)e * I_DIM * H_DIM;
    __shared__ float As[DK][DM + 1];
    __shared__ float Bs[DK][DN];
    __shared__ int toks[DM];
    __shared__ int slots[DM];
    __shared__ float wts[DM];
    int tid = threadIdx.x;
    if (tid < DM) {
        int idx = mt0 + tid;
        bool valid = idx < nt;
        toks[tid] = valid ? btok[e * T_TOK + idx] : -1;
        slots[tid] = valid ? bslot[e * T_TOK + idx] : 0;
        wts[tid] = valid ? bwt[e * T_TOK + idx] : 0.f;
    }
    __syncthreads();
    int tx = tid % 16, ty = tid / 16;
    float acc[2][4] = {};
    for (int k0 = 0; k0 < I_DIM; k0 += DK) {
#pragma unroll
        for (int i = 0; i < 4; i++) {
            int el = tid + i * 256;
            int k = el % DK, mm = el / DK;
            As[k][mm] = (toks[mm] >= 0) ? act[(size_t)slots[mm] * I_DIM + k0 + k] : 0.f;
        }
#pragma unroll
        for (int i = 0; i < 8; i++) {
            int el = tid + i * 256;
            int n = el % DN, k = el / DN;
            Bs[k][n] = B[(size_t)(k0 + k) * H_DIM + n0 + n];
        }
        __syncthreads();
#pragma unroll
        for (int k = 0; k < DK; k++) {
            float a0 = As[k][ty * 2], a1 = As[k][ty * 2 + 1];
            float bv[4];
#pragma unroll
            for (int j = 0; j < 4; j++) bv[j] = Bs[k][tx * 4 + j];
#pragma unroll
            for (int j = 0; j < 4; j++) {
                acc[0][j] += a0 * bv[j];
                acc[1][j] += a1 * bv[j];
            }
        }
        __syncthreads();
    }
#pragma unroll
    for (int i = 0; i < 2; i++) {
        int mm = ty * 2 + i;
        if (mt0 + mm < nt) {
            int tk = toks[mm];
            float wt = wts[mm];
#pragma unroll
            for (int j = 0; j < 4; j++) {
                atomicAdd(&out[(size_t)tk * H_DIM + n0 + tx * 4 + j], wt * acc[i][j]);
            }
        }
    }
}

extern "C" void kernel_launch(void* const* d_in, const int* in_sizes, int n_in,
                              void* d_out, int out_size, void* d_ws, size_t ws_size,
                              hipStream_t stream) {
    const int* positions = (const int*)d_in[0];
    const float* hs = (const float*)d_in[1];
    const float* resid = (const float*)d_in[2];
    const float* w_qkv = (const float*)d_in[3];
    const float* w_o = (const float*)d_in[4];
    const float* q_norm_w = (const float*)d_in[5];
    const float* k_norm_w = (const float*)d_in[6];
    const float* ln1_w = (const float*)d_in[7];
    const float* ln2_w = (const float*)d_in[8];
    const float* gate_w = (const float*)d_in[9];
    const float* w_gu = (const float*)d_in[10];
    const float* w_dn = (const float*)d_in[11];

    float* out = (float*)d_out;            // [T,H] MoE output
    float* res2 = out + (size_t)T_TOK * H_DIM;  // [T,H] residual output

    float* ws = (float*)d_ws;
    float* res1  = ws;                 // 2M floats
    float* h1    = ws + 2097152;       // 2M (reused as attention output)
    float* qkv   = ws + 4194304;       // 3.1M
    float* oproj = ws + 7340032;       // 2M
    float* h2    = ws + 9437184;       // 2M
    float* act   = ws + 11534336;      // T*K*I = 1.57M
    int*   cnt   = (int*)(ws + 13107200);
    int*   btok  = cnt + 16;
    int*   bslot = btok + NEXP * T_TOK;
    float* bwt   = (float*)(bslot + NEXP * T_TOK);

    // 1. res1 = hs + resid; h1 = rms(res1)*ln1
    add_rms<<<T_TOK, 256, 0, stream>>>(hs, resid, ln1_w, res1, h1);
    // 2. qkv = h1 @ w_qkv
    gemm_f32<<<dim3(3072 / GBN, T_TOK / GBM), 256, 0, stream>>>(h1, w_qkv, qkv, T_TOK, 3072, H_DIM);
    // 3. q/k RMSNorm + RoPE in place
    qk_rope<<<T_TOK * (NH + NKV), 128, 0, stream>>>(qkv, q_norm_w, k_norm_w, positions);
    // 4. attention -> h1 (reuse)
    attn<<<T_TOK * NH / 4, 256, 0, stream>>>(qkv, h1);
    // 5. oproj = h1 @ w_o
    gemm_f32<<<dim3(H_DIM / GBN, T_TOK / GBM), 256, 0, stream>>>(h1, w_o, oproj, T_TOK, H_DIM, H_DIM);
    // 6. res2 = oproj + res1 (-> d_out); h2 = rms(res2)*ln2
    add_rms<<<T_TOK, 256, 0, stream>>>(oproj, res1, ln2_w, res2, h2);
    // 7. router
    hipMemsetAsync(cnt, 0, NEXP * sizeof(int), stream);
    router<<<T_TOK, 256, 0, stream>>>(h2, gate_w, cnt, btok, bslot, bwt);
    // 8. MoE
    hipMemsetAsync(out, 0, (size_t)T_TOK * H_DIM * sizeof(float), stream);
    moe_gate_up<<<dim3(I_DIM / AN, T_TOK / AM, NEXP), 256, 0, stream>>>(h2, w_gu, cnt, btok, bslot, act);
    moe_down<<<dim3(H_DIM / DN, T_TOK / DM, NEXP), 256, 0, stream>>>(act, w_dn, cnt, btok, bslot, bwt, out);
}

// Round 2
// 1368.064 us; speedup vs baseline: 1.4558x; 1.4558x over previous
//
#include <hip/hip_runtime.h>
#include <hip/hip_bf16.h>

#define T_TOK 1024
#define H_DIM 2048
#define NH 16
#define NKV 4
#define HD 128
#define NEXP 8
#define TOPK 2
#define I_DIM 768
#define EPSF 1e-6f

// ---------------- fused residual add + RMSNorm ----------------
__global__ __launch_bounds__(256) void add_rms(const float* __restrict__ a,
                                               const float* __restrict__ b,
                                               const float* __restrict__ w,
                                               float* __restrict__ res,
                                               float* __restrict__ h) {
    int t = blockIdx.x, tid = threadIdx.x;
    float v[8];
    float ss = 0.f;
#pragma unroll
    for (int i = 0; i < 8; i++) {
        int idx = t * H_DIM + tid + i * 256;
        v[i] = a[idx] + b[idx];
        res[idx] = v[i];
        ss += v[i] * v[i];
    }
#pragma unroll
    for (int o = 32; o; o >>= 1) ss += __shfl_down(ss, o);
    __shared__ float red[4];
    if ((tid & 63) == 0) red[tid >> 6] = ss;
    __syncthreads();
    float tot = red[0] + red[1] + red[2] + red[3];
    float scale = rsqrtf(tot / (float)H_DIM + EPSF);
#pragma unroll
    for (int i = 0; i < 8; i++) {
        int c = tid + i * 256;
        h[t * H_DIM + c] = v[i] * scale * w[c];
    }
}

// ---------------- generic tiled f32 GEMM: C[M,N] = A[M,K] @ B[K,N] ----------------
#define GBM 64
#define GBN 64
#define GBK 16
__global__ __launch_bounds__(256) void gemm_f32(const float* __restrict__ A,
                                                const float* __restrict__ B,
                                                float* __restrict__ C,
                                                int M, int N, int Kd) {
    __shared__ float As[GBK][GBM + 1];
    __shared__ float Bs[GBK][GBN];
    int tid = threadIdx.x;
    int m0 = blockIdx.y * GBM, n0 = blockIdx.x * GBN;
    int tx = tid % 16, ty = tid / 16;
    float acc[4][4] = {};
    for (int k0 = 0; k0 < Kd; k0 += GBK) {
#pragma unroll
        for (int i = 0; i < 4; i++) {
            int e = tid + i * 256;
            int k = e % GBK, m = e / GBK;
            As[k][m] = A[(size_t)(m0 + m) * Kd + k0 + k];
        }
#pragma unroll
        for (int i = 0; i < 4; i++) {
            int e = tid + i * 256;
            int n = e % GBN, k = e / GBN;
            Bs[k][n] = B[(size_t)(k0 + k) * N + n0 + n];
        }
        __syncthreads();
#pragma unroll
        for (int k = 0; k < GBK; k++) {
            float av[4], bv[4];
#pragma unroll
            for (int i = 0; i < 4; i++) av[i] = As[k][ty * 4 + i];
#pragma unroll
            for (int j = 0; j < 4; j++) bv[j] = Bs[k][tx * 4 + j];
#pragma unroll
            for (int i = 0; i < 4; i++)
#pragma unroll
                for (int j = 0; j < 4; j++) acc[i][j] += av[i] * bv[j];
        }
        __syncthreads();
    }
#pragma unroll
    for (int i = 0; i < 4; i++)
#pragma unroll
        for (int j = 0; j < 4; j++)
            C[(size_t)(m0 + ty * 4 + i) * N + n0 + tx * 4 + j] = acc[i][j];
}

// ---------------- QK RMSNorm + neox RoPE (in-place on qkv) ----------------
__global__ __launch_bounds__(128) void qk_rope(float* __restrict__ qkv,
                                               const float* __restrict__ qw,
                                               const float* __restrict__ kw,
                                               const int* __restrict__ positions) {
    int t = blockIdx.x / (NH + NKV);
    int hh = blockIdx.x % (NH + NKV);
    float* x;
    const float* w;
    if (hh < NH) { x = qkv + (size_t)t * 3072 + hh * HD; w = qw; }
    else         { x = qkv + (size_t)t * 3072 + 2048 + (hh - NH) * HD; w = kw; }
    int tid = threadIdx.x;
    float v = x[tid];
    float ss = v * v;
#pragma unroll
    for (int o = 32; o; o >>= 1) ss += __shfl_down(ss, o);
    __shared__ float red[2];
    if ((tid & 63) == 0) red[tid >> 6] = ss;
    __syncthreads();
    float tot = red[0] + red[1];
    float scale = rsqrtf(tot / (float)HD + EPSF);
    float xn = v * scale * w[tid];
    __shared__ float buf[HD];
    buf[tid] = xn;
    __syncthreads();
    if (tid < 64) {
        float x1 = buf[tid], x2 = buf[tid + 64];
        float invf = expf(-((float)tid / 64.0f) * logf(1000000.0f));
        float ang = (float)positions[t] * invf;
        float c = cosf(ang), s = sinf(ang);
        x[tid] = x1 * c - x2 * s;
        x[tid + 64] = x2 * c + x1 * s;
    }
}

// ---------------- flash attention: 64-query tile per block, f32 tiled ----------------
#define FBQ 64
#define FBK 64
#define ATT_SCALE 0.08838834764831845f
__global__ __launch_bounds__(256) void attn_flash(const float* __restrict__ qkv,
                                                  float* __restrict__ o) {
    __shared__ float Qs[HD][FBQ];    // [d][row]  32 KB
    __shared__ float Ks[HD][FBK];    // [d][col]  32 KB
    __shared__ float Vs[FBK][HD];    // [j][d]    32 KB
    __shared__ float Ps[FBQ][FBK];   // 16 KB
    __shared__ float mrow[FBQ], lrow[FBQ], arow[FBQ];

    int qi = blockIdx.x;             // q-tile index (0..15)
    int h = blockIdx.y;              // head
    int q0 = qi * FBQ;
    int g = h >> 2;                  // kv head (NH/NKV = 4)
    int tid = threadIdx.x;
    int tx = tid & 15, ty = tid >> 4;

    // load Q tile transposed: Qs[d][row]
    {
        int r = tid >> 2;
        int c0 = (tid & 3) * 32;
        const float* qp = qkv + (size_t)(q0 + r) * 3072 + h * HD;
#pragma unroll
        for (int i = 0; i < 8; i++) {
            float4 v = *(const float4*)(qp + c0 + i * 4);
            Qs[c0 + i * 4 + 0][r] = v.x;
            Qs[c0 + i * 4 + 1][r] = v.y;
            Qs[c0 + i * 4 + 2][r] = v.z;
            Qs[c0 + i * 4 + 3][r] = v.w;
        }
    }
    if (tid < FBQ) { mrow[tid] = -1e30f; lrow[tid] = 0.f; }

    float acc[4][8] = {};  // rows ty*4+ii, dims tx*8+dd

    int nkt = qi + 1;
    for (int kt = 0; kt < nkt; kt++) {
        int k0 = kt * FBK;
        __syncthreads();  // previous tile's Ks/Vs/Ps fully consumed
        // load K (transposed) and V tiles
        {
            int r = tid >> 2;
            int c0 = (tid & 3) * 32;
            const float* kp = qkv + (size_t)(k0 + r) * 3072 + 2048 + g * HD;
            const float* vp = kp + 512;  // v offset within row: 2560 - 2048 + same g*HD
#pragma unroll
            for (int i = 0; i < 8; i++) {
                float4 v = *(const float4*)(kp + c0 + i * 4);
                Ks[c0 + i * 4 + 0][r] = v.x;
                Ks[c0 + i * 4 + 1][r] = v.y;
                Ks[c0 + i * 4 + 2][r] = v.z;
                Ks[c0 + i * 4 + 3][r] = v.w;
                *(float4*)(&Vs[r][c0 + i * 4]) = *(const float4*)(vp + c0 + i * 4);
            }
        }
        __syncthreads();

        // S tile: 4x4 per thread
        float s[4][4] = {};
        for (int d = 0; d < HD; d++) {
            float4 av = *(const float4*)(&Qs[d][ty * 4]);
            float4 bv = *(const float4*)(&Ks[d][tx * 4]);
            float a[4] = {av.x, av.y, av.z, av.w};
            float b[4] = {bv.x, bv.y, bv.z, bv.w};
#pragma unroll
            for (int ii = 0; ii < 4; ii++)
#pragma unroll
                for (int jj = 0; jj < 4; jj++) s[ii][jj] += a[ii] * b[jj];
        }

        bool lastTile = (kt == qi);
#pragma unroll
        for (int ii = 0; ii < 4; ii++) {
            int lr = ty * 4 + ii;  // local row
            float rm = -1e30f;
#pragma unroll
            for (int jj = 0; jj < 4; jj++) {
                s[ii][jj] *= ATT_SCALE;
                if (lastTile && (tx * 4 + jj > lr)) s[ii][jj] = -1e30f;
                rm = fmaxf(rm, s[ii][jj]);
            }
            rm = fmaxf(rm, __shfl_xor(rm, 1));
            rm = fmaxf(rm, __shfl_xor(rm, 2));
            rm = fmaxf(rm, __shfl_xor(rm, 4));
            rm = fmaxf(rm, __shfl_xor(rm, 8));
            float mo = mrow[lr];
            float mn = fmaxf(mo, rm);
            float rs = 0.f;
#pragma unroll
            for (int jj = 0; jj < 4; jj++) {
                float p = __expf(s[ii][jj] - mn);
                Ps[lr][tx * 4 + jj] = p;
                rs += p;
            }
            rs += __shfl_xor(rs, 1);
            rs += __shfl_xor(rs, 2);
            rs += __shfl_xor(rs, 4);
            rs += __shfl_xor(rs, 8);
            if (tx == 0) {
                float al = __expf(mo - mn);
                arow[lr] = al;
                lrow[lr] = lrow[lr] * al + rs;
                mrow[lr] = mn;
            }
        }
        __syncthreads();

        // PV: rows ty*4+ii, dims tx*8+dd
        float al[4];
#pragma unroll
        for (int ii = 0; ii < 4; ii++) {
            al[ii] = arow[ty * 4 + ii];
#pragma unroll
            for (int dd = 0; dd < 8; dd++) acc[ii][dd] *= al[ii];
        }
        for (int j = 0; j < FBK; j++) {
            float4 v0 = *(const float4*)(&Vs[j][tx * 8]);
            float4 v1 = *(const float4*)(&Vs[j][tx * 8 + 4]);
#pragma unroll
            for (int ii = 0; ii < 4; ii++) {
                float p = Ps[ty * 4 + ii][j];
                acc[ii][0] += p * v0.x; acc[ii][1] += p * v0.y;
                acc[ii][2] += p * v0.z; acc[ii][3] += p * v0.w;
                acc[ii][4] += p * v1.x; acc[ii][5] += p * v1.y;
                acc[ii][6] += p * v1.z; acc[ii][7] += p * v1.w;
            }
        }
    }
    __syncthreads();
#pragma unroll
    for (int ii = 0; ii < 4; ii++) {
        int lr = ty * 4 + ii;
        float inv = 1.f / lrow[lr];
        float* op = o + (size_t)(q0 + lr) * 2048 + h * HD + tx * 8;
        float4 o0 = make_float4(acc[ii][0] * inv, acc[ii][1] * inv, acc[ii][2] * inv, acc[ii][3] * inv);
        float4 o1 = make_float4(acc[ii][4] * inv, acc[ii][5] * inv, acc[ii][6] * inv, acc[ii][7] * inv);
        *(float4*)op = o0;
        *(float4*)(op + 4) = o1;
    }
}

// ---------------- router: softmax over 8 experts, top-2, bucket by expert ----------------
__global__ __launch_bounds__(256) void router(const float* __restrict__ h2,
                                              const float* __restrict__ gate_w,
                                              int* __restrict__ cnt,
                                              int* __restrict__ btok,
                                              int* __restrict__ bslot,
                                              float* __restrict__ bwt) {
    int t = blockIdx.x, tid = threadIdx.x;
    int e = tid & 7, c = tid >> 3;  // c in 0..31
    float part = 0.f;
    for (int i = 0; i < 64; i++) {
        int hh = c * 64 + i;
        part += h2[(size_t)t * H_DIM + hh] * gate_w[hh * NEXP + e];
    }
    __shared__ float red[256];
    red[tid] = part;
    __syncthreads();
    for (int s = 128; s >= 8; s >>= 1) {
        if (tid < s) red[tid] += red[tid + s];
        __syncthreads();
    }
    if (tid == 0) {
        float mx = -1e30f;
        for (int i = 0; i < NEXP; i++) mx = fmaxf(mx, red[i]);
        float p[NEXP];
        for (int i = 0; i < NEXP; i++) p[i] = expf(red[i] - mx);
        int i1 = 0;
        for (int i = 1; i < NEXP; i++) if (p[i] > p[i1]) i1 = i;
        int i2 = (i1 == 0) ? 1 : 0;
        for (int i = 0; i < NEXP; i++) if (i != i1 && p[i] > p[i2]) i2 = i;
        float denom = p[i1] + p[i2];
        float w1 = p[i1] / denom, w2 = p[i2] / denom;
        int pos = atomicAdd(&cnt[i1], 1);
        btok[i1 * T_TOK + pos] = t; bslot[i1 * T_TOK + pos] = t * 2; bwt[i1 * T_TOK + pos] = w1;
        pos = atomicAdd(&cnt[i2], 1);
        btok[i2 * T_TOK + pos] = t; bslot[i2 * T_TOK + pos] = t * 2 + 1; bwt[i2 * T_TOK + pos] = w2;
    }
}

// ---------------- grouped gate_up GEMM + SwiGLU: act[slot] = silu(h2@Wg) * (h2@Wu) ----------------
#define AM 32
#define AN 32
#define AK 32
__global__ __launch_bounds__(256) void moe_gate_up(const float* __restrict__ h2,
                                                   const float* __restrict__ w_gu,
                                                   const int* __restrict__ cnt,
                                                   const int* __restrict__ btok,
                                                   const int* __restrict__ bslot,
                                                   float* __restrict__ act) {
    int e = blockIdx.z;
    int nt = cnt[e];
    int mt0 = blockIdx.y * AM;
    if (mt0 >= nt) return;
    int n0 = blockIdx.x * AN;
    const float* B = w_gu + (size_t)e * H_DIM * (2 * I_DIM);
    __shared__ float As[AK][AM + 1];
    __shared__ float Bg[AK][AN];
    __shared__ float Bu[AK][AN];
    __shared__ int toks[AM];
    int tid = threadIdx.x;
    if (tid < AM) {
        int idx = mt0 + tid;
        toks[tid] = (idx < nt) ? btok[e * T_TOK + idx] : -1;
    }
    __syncthreads();
    int tx = tid % 16, ty = tid / 16;
    float accg[2][2] = {}, accu[2][2] = {};
    for (int k0 = 0; k0 < H_DIM; k0 += AK) {
#pragma unroll
        for (int i = 0; i < 4; i++) {
            int el = tid + i * 256;
            int k = el % AK, mm = el / AK;
            int tk = toks[mm];
            As[k][mm] = (tk >= 0) ? h2[(size_t)tk * H_DIM + k0 + k] : 0.f;
        }
#pragma unroll
        for (int i = 0; i < 4; i++) {
            int el = tid + i * 256;
            int n = el % AN, k = el / AN;
            const float* row = B + (size_t)(k0 + k) * (2 * I_DIM);
            Bg[k][n] = row[n0 + n];
            Bu[k][n] = row[I_DIM + n0 + n];
        }
        __syncthreads();
#pragma unroll
        for (int k = 0; k < AK; k++) {
            float a0 = As[k][ty * 2], a1 = As[k][ty * 2 + 1];
            float g0 = Bg[k][tx * 2], g1 = Bg[k][tx * 2 + 1];
            float u0 = Bu[k][tx * 2], u1 = Bu[k][tx * 2 + 1];
            accg[0][0] += a0 * g0; accg[0][1] += a0 * g1;
            accg[1][0] += a1 * g0; accg[1][1] += a1 * g1;
            accu[0][0] += a0 * u0; accu[0][1] += a0 * u1;
            accu[1][0] += a1 * u0; accu[1][1] += a1 * u1;
        }
        __syncthreads();
    }
#pragma unroll
    for (int i = 0; i < 2; i++) {
        int mm = ty * 2 + i;
        if (mt0 + mm < nt) {
            int slot = bslot[e * T_TOK + mt0 + mm];
#pragma unroll
            for (int j = 0; j < 2; j++) {
                float g = accg[i][j], u = accu[i][j];
                float sg = g / (1.f + expf(-g));
                act[(size_t)slot * I_DIM + n0 + tx * 2 + j] = sg * u;
            }
        }
    }
}

// ---------------- grouped down GEMM + weighted scatter-add ----------------
#define DM 32
#define DN 64
#define DK 32
__global__ __launch_bounds__(256) void moe_down(const float* __restrict__ act,
                                                const float* __restrict__ w_down,
                                                const int* __restrict__ cnt,
                                                const int* __restrict__ btok,
                                                const int* __restrict__ bslot,
                                                const float* __restrict__ bwt,
                                                float* __restrict__ out) {
    int e = blockIdx.z;
    int nt = cnt[e];
    int mt0 = blockIdx.y * DM;
    if (mt0 >= nt) return;
    int n0 = blockIdx.x * DN;
    const float* B = w_down + (size_t)e * I_DIM * H_DIM;
    __shared__ float As[DK][DM + 1];
    __shared__ float Bs[DK][DN];
    __shared__ int toks[DM];
    __shared__ int slots[DM];
    __shared__ float wts[DM];
    int tid = threadIdx.x;
    if (tid < DM) {
        int idx = mt0 + tid;
        bool valid = idx < nt;
        toks[tid] = valid ? btok[e * T_TOK + idx] : -1;
        slots[tid] = valid ? bslot[e * T_TOK + idx] : 0;
        wts[tid] = valid ? bwt[e * T_TOK + idx] : 0.f;
    }
    __syncthreads();
    int tx = tid % 16, ty = tid / 16;
    float acc[2][4] = {};
    for (int k0 = 0; k0 < I_DIM; k0 += DK) {
#pragma unroll
        for (int i = 0; i < 4; i++) {
            int el = tid + i * 256;
            int k = el % DK, mm = el / DK;
            As[k][mm] = (toks[mm] >= 0) ? act[(size_t)slots[mm] * I_DIM + k0 + k] : 0.f;
        }
#pragma unroll
        for (int i = 0; i < 8; i++) {
            int el = tid + i * 256;
            int n = el % DN, k = el / DN;
            Bs[k][n] = B[(size_t)(k0 + k) * H_DIM + n0 + n];
        }
        __syncthreads();
#pragma unroll
        for (int k = 0; k < DK; k++) {
            float a0 = As[k][ty * 2], a1 = As[k][ty * 2 + 1];
            float bv[4];
#pragma unroll
            for (int j = 0; j < 4; j++) bv[j] = Bs[k][tx * 4 + j];
#pragma unroll
            for (int j = 0; j < 4; j++) {
                acc[0][j] += a0 * bv[j];
                acc[1][j] += a1 * bv[j];
            }
        }
        __syncthreads();
    }
#pragma unroll
    for (int i = 0; i < 2; i++) {
        int mm = ty * 2 + i;
        if (mt0 + mm < nt) {
            int tk = toks[mm];
            float wt = wts[mm];
#pragma unroll
            for (int j = 0; j < 4; j++) {
                atomicAdd(&out[(size_t)tk * H_DIM + n0 + tx * 4 + j], wt * acc[i][j]);
            }
        }
    }
}

extern "C" void kernel_launch(void* const* d_in, const int* in_sizes, int n_in,
                              void* d_out, int out_size, void* d_ws, size_t ws_size,
                              hipStream_t stream) {
    const int* positions = (const int*)d_in[0];
    const float* hs = (const float*)d_in[1];
    const float* resid = (const float*)d_in[2];
    const float* w_qkv = (const float*)d_in[3];
    const float* w_o = (const float*)d_in[4];
    const float* q_norm_w = (const float*)d_in[5];
    const float* k_norm_w = (const float*)d_in[6];
    const float* ln1_w = (const float*)d_in[7];
    const float* ln2_w = (const float*)d_in[8];
    const float* gate_w = (const float*)d_in[9];
    const float* w_gu = (const float*)d_in[10];
    const float* w_dn = (const float*)d_in[11];

    float* out = (float*)d_out;                 // [T,H] MoE output
    float* res2 = out + (size_t)T_TOK * H_DIM;  // [T,H] residual output

    float* ws = (float*)d_ws;
    float* res1  = ws;                 // 2M floats
    float* h1    = ws + 2097152;       // 2M (reused as attention output)
    float* qkv   = ws + 4194304;       // 3.1M
    float* oproj = ws + 7340032;       // 2M
    float* h2    = ws + 9437184;       // 2M
    float* act   = ws + 11534336;      // T*K*I = 1.57M
    int*   cnt   = (int*)(ws + 13107200);
    int*   btok  = cnt + 16;
    int*   bslot = btok + NEXP * T_TOK;
    float* bwt   = (float*)(bslot + NEXP * T_TOK);

    // 1. res1 = hs + resid; h1 = rms(res1)*ln1
    add_rms<<<T_TOK, 256, 0, stream>>>(hs, resid, ln1_w, res1, h1);
    // 2. qkv = h1 @ w_qkv
    gemm_f32<<<dim3(3072 / GBN, T_TOK / GBM), 256, 0, stream>>>(h1, w_qkv, qkv, T_TOK, 3072, H_DIM);
    // 3. q/k RMSNorm + RoPE in place
    qk_rope<<<T_TOK * (NH + NKV), 128, 0, stream>>>(qkv, q_norm_w, k_norm_w, positions);
    // 4. flash attention -> h1 (reuse)
    attn_flash<<<dim3(T_TOK / FBQ, NH), 256, 0, stream>>>(qkv, h1);
    // 5. oproj = h1 @ w_o
    gemm_f32<<<dim3(H_DIM / GBN, T_TOK / GBM), 256, 0, stream>>>(h1, w_o, oproj, T_TOK, H_DIM, H_DIM);
    // 6. res2 = oproj + res1 (-> d_out); h2 = rms(res2)*ln2
    add_rms<<<T_TOK, 256, 0, stream>>>(oproj, res1, ln2_w, res2, h2);
    // 7. router
    hipMemsetAsync(cnt, 0, NEXP * sizeof(int), stream);
    router<<<T_TOK, 256, 0, stream>>>(h2, gate_w, cnt, btok, bslot, bwt);
    // 8. MoE
    hipMemsetAsync(out, 0, (size_t)T_TOK * H_DIM * sizeof(float), stream);
    moe_gate_up<<<dim3(I_DIM / AN, T_TOK / AM, NEXP), 256, 0, stream>>>(h2, w_gu, cnt, btok, bslot, act);
    moe_down<<<dim3(H_DIM / DN, T_TOK / DM, NEXP), 256, 0, stream>>>(act, w_dn, cnt, btok, bslot, bwt, out);
}

// Round 4
// 1021.581 us; speedup vs baseline: 1.9495x; 1.3392x over previous
//
#include <hip/hip_runtime.h>
#include <hip/hip_bf16.h>

#define T_TOK 1024
#define H_DIM 2048
#define NH 16
#define NKV 4
#define HD 128
#define NEXP 8
#define I_DIM 768
#define EPSF 1e-6f

typedef unsigned short ushort_t;
typedef __attribute__((ext_vector_type(8))) _Float16 half8;
typedef __attribute__((ext_vector_type(4))) float f32x4;

__device__ __forceinline__ ushort_t f2h(float x) {
    _Float16 h = (_Float16)x;
    return __builtin_bit_cast(ushort_t, h);
}
__device__ __forceinline__ float h2f_(ushort_t u) {
    return (float)__builtin_bit_cast(_Float16, u);
}
__device__ __forceinline__ void gld16(const ushort_t* g, ushort_t* l) {
    __builtin_amdgcn_global_load_lds(
        (const __attribute__((address_space(1))) unsigned int*)g,
        (__attribute__((address_space(3))) unsigned int*)l, 16, 0, 0);
}

// ---------------- residual add + RMSNorm -> res f32, h as f16 hi/lo planes ----------------
__global__ __launch_bounds__(256) void add_rms1(const float* __restrict__ a,
                                                const float* __restrict__ b,
                                                const float* __restrict__ w,
                                                float* __restrict__ res,
                                                ushort_t* __restrict__ hh,
                                                ushort_t* __restrict__ hl) {
    int t = blockIdx.x, tid = threadIdx.x;
    float v[8];
    float ss = 0.f;
#pragma unroll
    for (int i = 0; i < 8; i++) {
        int idx = t * H_DIM + tid + i * 256;
        v[i] = a[idx] + b[idx];
        res[idx] = v[i];
        ss += v[i] * v[i];
    }
#pragma unroll
    for (int o = 32; o; o >>= 1) ss += __shfl_down(ss, o);
    __shared__ float red[4];
    if ((tid & 63) == 0) red[tid >> 6] = ss;
    __syncthreads();
    float tot = red[0] + red[1] + red[2] + red[3];
    float scale = rsqrtf(tot / (float)H_DIM + EPSF);
#pragma unroll
    for (int i = 0; i < 8; i++) {
        int c = tid + i * 256;
        float hv = v[i] * scale * w[c];
        ushort_t hi = f2h(hv);
        hh[t * H_DIM + c] = hi;
        hl[t * H_DIM + c] = f2h(hv - h2f_(hi));
    }
}

// ---------------- residual add + RMSNorm (f32 in) -> res f32, h f32, h f16 ----------------
__global__ __launch_bounds__(256) void add_rms2(const float* __restrict__ a,
                                                const float* __restrict__ b,
                                                const float* __restrict__ w,
                                                float* __restrict__ res,
                                                float* __restrict__ hf,
                                                ushort_t* __restrict__ hh) {
    int t = blockIdx.x, tid = threadIdx.x;
    float v[8];
    float ss = 0.f;
#pragma unroll
    for (int i = 0; i < 8; i++) {
        int idx = t * H_DIM + tid + i * 256;
        v[i] = a[idx] + b[idx];
        res[idx] = v[i];
        ss += v[i] * v[i];
    }
#pragma unroll
    for (int o = 32; o; o >>= 1) ss += __shfl_down(ss, o);
    __shared__ float red[4];
    if ((tid & 63) == 0) red[tid >> 6] = ss;
    __syncthreads();
    float tot = red[0] + red[1] + red[2] + red[3];
    float scale = rsqrtf(tot / (float)H_DIM + EPSF);
#pragma unroll
    for (int i = 0; i < 8; i++) {
        int c = tid + i * 256;
        float hv = v[i] * scale * w[c];
        hf[t * H_DIM + c] = hv;
        hh[t * H_DIM + c] = f2h(hv);
    }
}

// ---------------- cast+transpose f32 [R][C(ld)] -> f16 hi/lo [C][R] ----------------
__global__ __launch_bounds__(256) void castT_hl(const float* __restrict__ in,
                                                ushort_t* __restrict__ oh,
                                                ushort_t* __restrict__ ol,
                                                int R, int ld) {
    __shared__ float tile[32][33];
    int r0 = blockIdx.y * 32, c0 = blockIdx.x * 32;
    int tx = threadIdx.x & 31, ty = threadIdx.x >> 5;
#pragma unroll
    for (int i = 0; i < 4; i++)
        tile[ty + 8 * i][tx] = in[(size_t)(r0 + ty + 8 * i) * ld + c0 + tx];
    __syncthreads();
#pragma unroll
    for (int i = 0; i < 4; i++) {
        float v = tile[tx][ty + 8 * i];
        ushort_t hi = f2h(v);
        size_t idx = (size_t)(c0 + ty + 8 * i) * R + r0 + tx;
        oh[idx] = hi;
        ol[idx] = f2h(v - h2f_(hi));
    }
}

// ---------------- cast+transpose f32 [R][C(ld)] -> f16 [C][R], z-batched ----------------
__global__ __launch_bounds__(256) void castT_h(const float* __restrict__ in,
                                               ushort_t* __restrict__ out,
                                               int R, int ld, size_t zstride) {
    in += (size_t)blockIdx.z * zstride;
    out += (size_t)blockIdx.z * zstride;
    __shared__ float tile[32][33];
    int r0 = blockIdx.y * 32, c0 = blockIdx.x * 32;
    int tx = threadIdx.x & 31, ty = threadIdx.x >> 5;
#pragma unroll
    for (int i = 0; i < 4; i++)
        tile[ty + 8 * i][tx] = in[(size_t)(r0 + ty + 8 * i) * ld + c0 + tx];
    __syncthreads();
#pragma unroll
    for (int i = 0; i < 4; i++)
        out[(size_t)(c0 + ty + 8 * i) * R + r0 + tx] = f2h(tile[tx][ty + 8 * i]);
}

// ------- split-f16 MFMA GEMM: C[M,N] (f32) = (Ah+Al)[M,K] @ (Bh+Bl)[N,K]^T -------
__global__ __launch_bounds__(256) void gemm_f16x3(const ushort_t* __restrict__ Ah,
                                                  const ushort_t* __restrict__ Al_,
                                                  const ushort_t* __restrict__ Bh,
                                                  const ushort_t* __restrict__ Bl_,
                                                  float* __restrict__ C,
                                                  int ldc, int K) {
    __shared__ ushort_t sAh[4096], sAl[4096], sBh[4096], sBl[4096];
    int tid = threadIdx.x, lane = tid & 63, wv = tid >> 6;
    int m0 = blockIdx.y * 128, n0 = blockIdx.x * 128;
    int wm = (wv & 1) * 64, wn = (wv >> 1) * 64;
    int fr = lane & 15, fq = lane >> 4;
    f32x4 acc[4][4];
#pragma unroll
    for (int i = 0; i < 4; i++)
#pragma unroll
        for (int j = 0; j < 4; j++) acc[i][j] = {0.f, 0.f, 0.f, 0.f};

    size_t aoff = (size_t)(m0 + wv * 32 + (lane >> 2)) * K + (lane & 3) * 8;
    size_t boff = (size_t)(n0 + wv * 32 + (lane >> 2)) * K + (lane & 3) * 8;
    const ushort_t* gAh = Ah + aoff;
    const ushort_t* gAl = Al_ + aoff;
    const ushort_t* gBh = Bh + boff;
    const ushort_t* gBl = Bl_ + boff;

    for (int k0 = 0; k0 < K; k0 += 32) {
        gld16(gAh, &sAh[(wv * 32) * 32]);
        gld16(gAh + (size_t)16 * K, &sAh[(wv * 32 + 16) * 32]);
        gld16(gAl, &sAl[(wv * 32) * 32]);
        gld16(gAl + (size_t)16 * K, &sAl[(wv * 32 + 16) * 32]);
        gld16(gBh, &sBh[(wv * 32) * 32]);
        gld16(gBh + (size_t)16 * K, &sBh[(wv * 32 + 16) * 32]);
        gld16(gBl, &sBl[(wv * 32) * 32]);
        gld16(gBl + (size_t)16 * K, &sBl[(wv * 32 + 16) * 32]);
        gAh += 32; gAl += 32; gBh += 32; gBl += 32;
        __syncthreads();
        half8 ah[4], al[4], bh[4], bl[4];
#pragma unroll
        for (int i = 0; i < 4; i++) {
            int off = (wm + i * 16 + fr) * 32 + fq * 8;
            ah[i] = *(const half8*)&sAh[off];
            al[i] = *(const half8*)&sAl[off];
        }
#pragma unroll
        for (int j = 0; j < 4; j++) {
            int off = (wn + j * 16 + fr) * 32 + fq * 8;
            bh[j] = *(const half8*)&sBh[off];
            bl[j] = *(const half8*)&sBl[off];
        }
#pragma unroll
        for (int i = 0; i < 4; i++)
#pragma unroll
            for (int j = 0; j < 4; j++) {
                acc[i][j] = __builtin_amdgcn_mfma_f32_16x16x32_f16(ah[i], bh[j], acc[i][j], 0, 0, 0);
                acc[i][j] = __builtin_amdgcn_mfma_f32_16x16x32_f16(ah[i], bl[j], acc[i][j], 0, 0, 0);
                acc[i][j] = __builtin_amdgcn_mfma_f32_16x16x32_f16(al[i], bh[j], acc[i][j], 0, 0, 0);
            }
        __syncthreads();
    }
#pragma unroll
    for (int i = 0; i < 4; i++)
#pragma unroll
        for (int j = 0; j < 4; j++)
#pragma unroll
            for (int r = 0; r < 4; r++) {
                int row = m0 + wm + i * 16 + fq * 4 + r;
                int col = n0 + wn + j * 16 + fr;
                C[(size_t)row * ldc + col] = acc[i][j][r];
            }
}

// ---------------- grouped f16 MFMA GEMM (MoE): gathered A rows, scattered C rows ----------------
__global__ __launch_bounds__(256) void moe_gemm(const ushort_t* __restrict__ Ab,
                                                const ushort_t* __restrict__ BtAll,
                                                const int* __restrict__ cnt,
                                                const int* __restrict__ ridx_g,
                                                const int* __restrict__ oidx_g,
                                                ushort_t* __restrict__ Cout,
                                                int N, int K, int ebase) {
    int e = ebase + blockIdx.z;
    int nt = cnt[e];
    int mt0 = blockIdx.y * 128;
    if (mt0 >= nt) return;
    const ushort_t* Bt = BtAll + (size_t)blockIdx.z * N * K;
    int n0 = blockIdx.x * 128;
    __shared__ ushort_t Al[4096];
    __shared__ ushort_t Bl[4096];
    __shared__ int ridx[128], oidx[128];
    int tid = threadIdx.x, lane = tid & 63, wv = tid >> 6;
    if (tid < 128) {
        int ii = mt0 + tid;
        bool v = ii < nt;
        ridx[tid] = v ? ridx_g[e * T_TOK + ii] : -1;
        oidx[tid] = v ? oidx_g[e * T_TOK + ii] : -1;
    }
    __syncthreads();
    int wm = (wv & 1) * 64, wn = (wv >> 1) * 64;
    int fr = lane & 15, fq = lane >> 4;
    f32x4 acc[4][4];
#pragma unroll
    for (int i = 0; i < 4; i++)
#pragma unroll
        for (int j = 0; j < 4; j++) acc[i][j] = {0.f, 0.f, 0.f, 0.f};

    int arow = tid >> 1, akoff = (tid & 1) * 16;
    int ra = ridx[arow];
    const ushort_t* asrc = (ra >= 0) ? (Ab + (size_t)ra * K + akoff) : (const ushort_t*)0;
    const ushort_t* gB = Bt + (size_t)(n0 + wv * 32 + (lane >> 2)) * K + (lane & 3) * 8;

    for (int k0 = 0; k0 < K; k0 += 32) {
        uint4 v0 = {0, 0, 0, 0}, v1 = {0, 0, 0, 0};
        if (ra >= 0) {
            v0 = *(const uint4*)(asrc);
            v1 = *(const uint4*)(asrc + 8);
            asrc += 32;
        }
        gld16(gB, &Bl[(wv * 32) * 32]);
        gld16(gB + (size_t)16 * K, &Bl[(wv * 32 + 16) * 32]);
        gB += 32;
        *(uint4*)&Al[arow * 32 + akoff] = v0;
        *(uint4*)&Al[arow * 32 + akoff + 8] = v1;
        __syncthreads();
        half8 af[4], bfr[4];
#pragma unroll
        for (int i = 0; i < 4; i++) af[i] = *(const half8*)&Al[(wm + i * 16 + fr) * 32 + fq * 8];
#pragma unroll
        for (int j = 0; j < 4; j++) bfr[j] = *(const half8*)&Bl[(wn + j * 16 + fr) * 32 + fq * 8];
#pragma unroll
        for (int i = 0; i < 4; i++)
#pragma unroll
            for (int j = 0; j < 4; j++)
                acc[i][j] = __builtin_amdgcn_mfma_f32_16x16x32_f16(af[i], bfr[j], acc[i][j], 0, 0, 0);
        __syncthreads();
    }
#pragma unroll
    for (int i = 0; i < 4; i++)
#pragma unroll
        for (int j = 0; j < 4; j++)
#pragma unroll
            for (int r = 0; r < 4; r++) {
                int lr = wm + i * 16 + fq * 4 + r;
                if (mt0 + lr < nt) {
                    int orow = oidx[lr];
                    Cout[(size_t)orow * N + n0 + wn + j * 16 + fr] = f2h(acc[i][j][r]);
                }
            }
}

// ---------------- QK RMSNorm + neox RoPE (in-place on f32 qkv) ----------------
__global__ __launch_bounds__(128) void qk_rope(float* __restrict__ qkv,
                                               const float* __restrict__ qw,
                                               const float* __restrict__ kw,
                                               const int* __restrict__ positions) {
    int t = blockIdx.x / (NH + NKV);
    int hh = blockIdx.x % (NH + NKV);
    float* x;
    const float* w;
    if (hh < NH) { x = qkv + (size_t)t * 3072 + hh * HD; w = qw; }
    else         { x = qkv + (size_t)t * 3072 + 2048 + (hh - NH) * HD; w = kw; }
    int tid = threadIdx.x;
    float v = x[tid];
    float ss = v * v;
#pragma unroll
    for (int o = 32; o; o >>= 1) ss += __shfl_down(ss, o);
    __shared__ float red[2];
    if ((tid & 63) == 0) red[tid >> 6] = ss;
    __syncthreads();
    float tot = red[0] + red[1];
    float scale = rsqrtf(tot / (float)HD + EPSF);
    float xn = v * scale * w[tid];
    __shared__ float buf[HD];
    buf[tid] = xn;
    __syncthreads();
    if (tid < 64) {
        float x1 = buf[tid], x2 = buf[tid + 64];
        float invf = expf(-((float)tid / 64.0f) * logf(1000000.0f));
        float ang = (float)positions[t] * invf;
        float c = cosf(ang), s = sinf(ang);
        x[tid] = x1 * c - x2 * s;
        x[tid + 64] = x2 * c + x1 * s;
    }
}

// ---------------- flash attention f32; output as f16 hi/lo planes ----------------
#define FBQ 64
#define FBK 64
#define ATT_SCALE 0.08838834764831845f
__global__ __launch_bounds__(256) void attn_flash(const float* __restrict__ qkv,
                                                  ushort_t* __restrict__ ohp,
                                                  ushort_t* __restrict__ olp) {
    __shared__ float Qs[HD][FBQ];
    __shared__ float Ks[HD][FBK];
    __shared__ float Vs[FBK][HD];
    __shared__ float Ps[FBQ][FBK];
    __shared__ float mrow[FBQ], lrow[FBQ], arow[FBQ];

    int qi = blockIdx.x;
    int h = blockIdx.y;
    int q0 = qi * FBQ;
    int g = h >> 2;
    int tid = threadIdx.x;
    int tx = tid & 15, ty = tid >> 4;

    {
        int r = tid >> 2, c0 = (tid & 3) * 32;
        const float* qp = qkv + (size_t)(q0 + r) * 3072 + h * HD;
#pragma unroll
        for (int i = 0; i < 8; i++) {
            float4 v = *(const float4*)(qp + c0 + i * 4);
            Qs[c0 + i * 4 + 0][r] = v.x;
            Qs[c0 + i * 4 + 1][r] = v.y;
            Qs[c0 + i * 4 + 2][r] = v.z;
            Qs[c0 + i * 4 + 3][r] = v.w;
        }
    }
    if (tid < FBQ) { mrow[tid] = -1e30f; lrow[tid] = 0.f; }

    float acc[4][8] = {};

    int nkt = qi + 1;
    for (int kt = 0; kt < nkt; kt++) {
        int k0 = kt * FBK;
        __syncthreads();
        {
            int r = tid >> 2, c0 = (tid & 3) * 32;
            const float* kp = qkv + (size_t)(k0 + r) * 3072 + 2048 + g * HD;
            const float* vp = kp + 512;
#pragma unroll
            for (int i = 0; i < 8; i++) {
                float4 v = *(const float4*)(kp + c0 + i * 4);
                Ks[c0 + i * 4 + 0][r] = v.x;
                Ks[c0 + i * 4 + 1][r] = v.y;
                Ks[c0 + i * 4 + 2][r] = v.z;
                Ks[c0 + i * 4 + 3][r] = v.w;
                *(float4*)(&Vs[r][c0 + i * 4]) = *(const float4*)(vp + c0 + i * 4);
            }
        }
        __syncthreads();

        float s[4][4] = {};
        for (int d = 0; d < HD; d++) {
            float4 av = *(const float4*)(&Qs[d][ty * 4]);
            float4 bv = *(const float4*)(&Ks[d][tx * 4]);
            float a[4] = {av.x, av.y, av.z, av.w};
            float b[4] = {bv.x, bv.y, bv.z, bv.w};
#pragma unroll
            for (int ii = 0; ii < 4; ii++)
#pragma unroll
                for (int jj = 0; jj < 4; jj++) s[ii][jj] += a[ii] * b[jj];
        }

        bool lastTile = (kt == qi);
#pragma unroll
        for (int ii = 0; ii < 4; ii++) {
            int lr = ty * 4 + ii;
            float rm = -1e30f;
#pragma unroll
            for (int jj = 0; jj < 4; jj++) {
                s[ii][jj] *= ATT_SCALE;
                if (lastTile && (tx * 4 + jj > lr)) s[ii][jj] = -1e30f;
                rm = fmaxf(rm, s[ii][jj]);
            }
            rm = fmaxf(rm, __shfl_xor(rm, 1));
            rm = fmaxf(rm, __shfl_xor(rm, 2));
            rm = fmaxf(rm, __shfl_xor(rm, 4));
            rm = fmaxf(rm, __shfl_xor(rm, 8));
            float mo = mrow[lr];
            float mn = fmaxf(mo, rm);
            float rs = 0.f;
#pragma unroll
            for (int jj = 0; jj < 4; jj++) {
                float p = __expf(s[ii][jj] - mn);
                Ps[lr][tx * 4 + jj] = p;
                rs += p;
            }
            rs += __shfl_xor(rs, 1);
            rs += __shfl_xor(rs, 2);
            rs += __shfl_xor(rs, 4);
            rs += __shfl_xor(rs, 8);
            if (tx == 0) {
                float al = __expf(mo - mn);
                arow[lr] = al;
                lrow[lr] = lrow[lr] * al + rs;
                mrow[lr] = mn;
            }
        }
        __syncthreads();

        float al[4];
#pragma unroll
        for (int ii = 0; ii < 4; ii++) {
            al[ii] = arow[ty * 4 + ii];
#pragma unroll
            for (int dd = 0; dd < 8; dd++) acc[ii][dd] *= al[ii];
        }
        for (int j = 0; j < FBK; j++) {
            float4 v0 = *(const float4*)(&Vs[j][tx * 8]);
            float4 v1 = *(const float4*)(&Vs[j][tx * 8 + 4]);
#pragma unroll
            for (int ii = 0; ii < 4; ii++) {
                float p = Ps[ty * 4 + ii][j];
                acc[ii][0] += p * v0.x; acc[ii][1] += p * v0.y;
                acc[ii][2] += p * v0.z; acc[ii][3] += p * v0.w;
                acc[ii][4] += p * v1.x; acc[ii][5] += p * v1.y;
                acc[ii][6] += p * v1.z; acc[ii][7] += p * v1.w;
            }
        }
    }
    __syncthreads();
#pragma unroll
    for (int ii = 0; ii < 4; ii++) {
        int lr = ty * 4 + ii;
        float inv = 1.f / lrow[lr];
        size_t base = (size_t)(q0 + lr) * 2048 + h * HD + tx * 8;
        ushort_t th[8], tl[8];
#pragma unroll
        for (int dd = 0; dd < 8; dd++) {
            float v = acc[ii][dd] * inv;
            ushort_t hi = f2h(v);
            th[dd] = hi;
            tl[dd] = f2h(v - h2f_(hi));
        }
        *(uint4*)&ohp[base] = *(uint4*)th;
        *(uint4*)&olp[base] = *(uint4*)tl;
    }
}

// ---------------- router: softmax over 8 experts, top-2, bucket by expert ----------------
__global__ __launch_bounds__(256) void router(const float* __restrict__ h2,
                                              const float* __restrict__ gate_w,
                                              int* __restrict__ cnt,
                                              int* __restrict__ btok,
                                              int* __restrict__ bslot,
                                              float* __restrict__ wslot) {
    int t = blockIdx.x, tid = threadIdx.x;
    int e = tid & 7, c = tid >> 3;
    float part = 0.f;
    for (int i = 0; i < 64; i++) {
        int hh = c * 64 + i;
        part += h2[(size_t)t * H_DIM + hh] * gate_w[hh * NEXP + e];
    }
    __shared__ float red[256];
    red[tid] = part;
    __syncthreads();
    for (int s = 128; s >= 8; s >>= 1) {
        if (tid < s) red[tid] += red[tid + s];
        __syncthreads();
    }
    if (tid == 0) {
        float mx = -1e30f;
        for (int i = 0; i < NEXP; i++) mx = fmaxf(mx, red[i]);
        float p[NEXP];
        for (int i = 0; i < NEXP; i++) p[i] = expf(red[i] - mx);
        int i1 = 0;
        for (int i = 1; i < NEXP; i++) if (p[i] > p[i1]) i1 = i;
        int i2 = (i1 == 0) ? 1 : 0;
        for (int i = 0; i < NEXP; i++) if (i != i1 && p[i] > p[i2]) i2 = i;
        float denom = p[i1] + p[i2];
        wslot[2 * t] = p[i1] / denom;
        wslot[2 * t + 1] = p[i2] / denom;
        int pos = atomicAdd(&cnt[i1], 1);
        btok[i1 * T_TOK + pos] = t; bslot[i1 * T_TOK + pos] = 2 * t;
        pos = atomicAdd(&cnt[i2], 1);
        btok[i2 * T_TOK + pos] = t; bslot[i2 * T_TOK + pos] = 2 * t + 1;
    }
}

// ---------------- SwiGLU: gu f16 [2048][1536] -> act f16 [2048][768] ----------------
__global__ __launch_bounds__(256) void swiglu(const ushort_t* __restrict__ gu,
                                              ushort_t* __restrict__ act) {
    int idx = blockIdx.x * 256 + threadIdx.x;
    int s = idx / I_DIM, i = idx - s * I_DIM;
    float g = h2f_(gu[(size_t)s * (2 * I_DIM) + i]);
    float u = h2f_(gu[(size_t)s * (2 * I_DIM) + I_DIM + i]);
    act[idx] = f2h(g / (1.f + expf(-g)) * u);
}

// ---------------- combine: out[t] = w0*dbuf[2t] + w1*dbuf[2t+1] ----------------
__global__ __launch_bounds__(256) void combine(const ushort_t* __restrict__ dbuf,
                                               const float* __restrict__ wslot,
                                               float* __restrict__ out) {
    int idx = blockIdx.x * 256 + threadIdx.x;
    int t = idx >> 11;
    out[idx] = wslot[2 * t] * h2f_(dbuf[(size_t)(2 * t) * H_DIM + (idx & 2047)]) +
               wslot[2 * t + 1] * h2f_(dbuf[(size_t)(2 * t + 1) * H_DIM + (idx & 2047)]);
}

extern "C" void kernel_launch(void* const* d_in, const int* in_sizes, int n_in,
                              void* d_out, int out_size, void* d_ws, size_t ws_size,
                              hipStream_t stream) {
    const int* positions = (const int*)d_in[0];
    const float* hs = (const float*)d_in[1];
    const float* resid = (const float*)d_in[2];
    const float* w_qkv = (const float*)d_in[3];
    const float* w_o = (const float*)d_in[4];
    const float* q_norm_w = (const float*)d_in[5];
    const float* k_norm_w = (const float*)d_in[6];
    const float* ln1_w = (const float*)d_in[7];
    const float* ln2_w = (const float*)d_in[8];
    const float* gate_w = (const float*)d_in[9];
    const float* w_gu = (const float*)d_in[10];
    const float* w_dn = (const float*)d_in[11];

    float* out = (float*)d_out;
    float* res2 = out + (size_t)T_TOK * H_DIM;

    const size_t MB = 1ull << 20;
    char* W = (char*)d_ws;
    // region A: 0-8 MiB
    float*    res1   = (float*)(W + 0);          // live steps 2-8
    ushort_t* dbuf   = (ushort_t*)(W + 0);       // f16 [2048][2048], live 12-13
    // region B: 8-16 MiB
    ushort_t* h1h    = (ushort_t*)(W + 8 * MB);  // live 2-3
    ushort_t* h1l    = (ushort_t*)(W + 12 * MB);
    ushort_t* ohp    = (ushort_t*)(W + 8 * MB);  // live 6-7
    ushort_t* olp    = (ushort_t*)(W + 12 * MB);
    ushort_t* h2h    = (ushort_t*)(W + 8 * MB);  // live 8-12
    ushort_t* actb   = (ushort_t*)(W + 12 * MB); // 3 MiB, live 11-12
    // region C: 16-28 MiB
    float*    qkvf   = (float*)(W + 16 * MB);    // 12 MiB, live 3-6
    float*    oprojf = (float*)(W + 16 * MB);    // 8 MiB, live 7-8
    ushort_t* gub    = (ushort_t*)(W + 16 * MB); // 6 MiB, live 10-11
    // region D: 28-44 MiB (weight transposes)
    ushort_t* wTh    = (ushort_t*)(W + 28 * MB); // qkv chunk hi 6 MiB / w_o hi 8 MiB / moe 12 MiB
    ushort_t* wTl_q  = (ushort_t*)(W + 34 * MB); // qkv chunk lo 6 MiB
    ushort_t* wTl_o  = (ushort_t*)(W + 36 * MB); // w_o lo 8 MiB (28-36 hi, 36-44 lo)
    // region E: 40-48 MiB
    float*    h2f    = (float*)(W + 40 * MB);    // 8 MiB, live 8-9
    // buckets: 48 MiB+
    int*      cnt    = (int*)(W + 48 * MB);
    int*      btok   = cnt + 16;
    int*      bslot  = btok + NEXP * T_TOK;
    float*    wslot  = (float*)(bslot + NEXP * T_TOK);

    // 1+2. res1 = hs + resid; h1 = rms(res1)*ln1 as f16 hi/lo
    add_rms1<<<T_TOK, 256, 0, stream>>>(hs, resid, ln1_w, res1, h1h, h1l);
    // 3. qkv = h1 @ w_qkv in two N-chunks of 1536 (f16x3 split GEMM, f32 out)
    for (int c = 0; c < 2; c++) {
        castT_hl<<<dim3(1536 / 32, 2048 / 32), 256, 0, stream>>>(
            w_qkv + c * 1536, wTh, wTl_q, 2048, 3072);
        gemm_f16x3<<<dim3(1536 / 128, 1024 / 128), 256, 0, stream>>>(
            h1h, h1l, wTh, wTl_q, qkvf + c * 1536, 3072, 2048);
    }
    // 4. q/k RMSNorm + RoPE in place (f32)
    qk_rope<<<T_TOK * (NH + NKV), 128, 0, stream>>>(qkvf, q_norm_w, k_norm_w, positions);
    // 5. w_o transpose hi/lo
    castT_hl<<<dim3(2048 / 32, 2048 / 32), 256, 0, stream>>>(w_o, wTh, wTl_o, 2048, 2048);
    // 6. flash attention (f32 math) -> o hi/lo f16 planes
    attn_flash<<<dim3(T_TOK / FBQ, NH), 256, 0, stream>>>(qkvf, ohp, olp);
    // 7. oproj = attn_out @ w_o (f16x3, f32 out)
    gemm_f16x3<<<dim3(2048 / 128, 1024 / 128), 256, 0, stream>>>(
        ohp, olp, wTh, wTl_o, oprojf, 2048, 2048);
    // 8. res2 = oproj + res1 (-> d_out); h2 f32 + f16
    add_rms2<<<T_TOK, 256, 0, stream>>>(oprojf, res1, ln2_w, res2, h2f, h2h);
    // 9. router (f32 logits)
    hipMemsetAsync(cnt, 0, NEXP * sizeof(int), stream);
    router<<<T_TOK, 256, 0, stream>>>(h2f, gate_w, cnt, btok, bslot, wslot);
    // 10. MoE gate_up in 4 chunks of 2 experts
    for (int c = 0; c < 4; c++) {
        castT_h<<<dim3(1536 / 32, 2048 / 32, 2), 256, 0, stream>>>(
            w_gu + (size_t)c * 2 * 2048 * 1536, wTh, 2048, 1536, (size_t)2048 * 1536);
        moe_gemm<<<dim3(1536 / 128, 8, 2), 256, 0, stream>>>(
            h2h, wTh, cnt, btok, bslot, gub, 1536, 2048, c * 2);
    }
    // 11. SwiGLU
    swiglu<<<(2048 * I_DIM) / 256, 256, 0, stream>>>(gub, actb);
    // 12. MoE down in 2 chunks of 4 experts
    for (int c = 0; c < 2; c++) {
        castT_h<<<dim3(2048 / 32, 768 / 32, 4), 256, 0, stream>>>(
            w_dn + (size_t)c * 4 * 768 * 2048, wTh, 768, 2048, (size_t)768 * 2048);
        moe_gemm<<<dim3(2048 / 128, 8, 4), 256, 0, stream>>>(
            actb, wTh, cnt, bslot, bslot, dbuf, 2048, 768, c * 4);
    }
    // 13. weighted combine
    combine<<<(T_TOK * H_DIM) / 256, 256, 0, stream>>>(dbuf, wslot, out);
}

// Round 5
// 927.457 us; speedup vs baseline: 2.1474x; 1.1015x over previous
//
#include <hip/hip_runtime.h>
#include <hip/hip_bf16.h>

#define T_TOK 1024
#define H_DIM 2048
#define NH 16
#define NKV 4
#define HD 128
#define NEXP 8
#define I_DIM 768
#define EPSF 1e-6f

typedef unsigned short ushort_t;
typedef __attribute__((ext_vector_type(8))) _Float16 half8;
typedef __attribute__((ext_vector_type(4))) float f32x4;
typedef __attribute__((ext_vector_type(4))) unsigned short us4;

__device__ __forceinline__ ushort_t f2h(float x) {
    _Float16 h = (_Float16)x;
    return __builtin_bit_cast(ushort_t, h);
}
__device__ __forceinline__ float h2f_(ushort_t u) {
    return (float)__builtin_bit_cast(_Float16, u);
}
__device__ __forceinline__ void gld16(const ushort_t* g, ushort_t* l) {
    __builtin_amdgcn_global_load_lds(
        (const __attribute__((address_space(1))) unsigned int*)g,
        (__attribute__((address_space(3))) unsigned int*)l, 16, 0, 0);
}

// ---------------- residual add + RMSNorm -> res f32, h as f16 hi/lo planes ----------------
__global__ __launch_bounds__(256) void add_rms1(const float* __restrict__ a,
                                                const float* __restrict__ b,
                                                const float* __restrict__ w,
                                                float* __restrict__ res,
                                                ushort_t* __restrict__ hh,
                                                ushort_t* __restrict__ hl) {
    int t = blockIdx.x, tid = threadIdx.x;
    float v[8];
    float ss = 0.f;
#pragma unroll
    for (int i = 0; i < 8; i++) {
        int idx = t * H_DIM + tid + i * 256;
        v[i] = a[idx] + b[idx];
        res[idx] = v[i];
        ss += v[i] * v[i];
    }
#pragma unroll
    for (int o = 32; o; o >>= 1) ss += __shfl_down(ss, o);
    __shared__ float red[4];
    if ((tid & 63) == 0) red[tid >> 6] = ss;
    __syncthreads();
    float tot = red[0] + red[1] + red[2] + red[3];
    float scale = rsqrtf(tot / (float)H_DIM + EPSF);
#pragma unroll
    for (int i = 0; i < 8; i++) {
        int c = tid + i * 256;
        float hv = v[i] * scale * w[c];
        ushort_t hi = f2h(hv);
        hh[t * H_DIM + c] = hi;
        hl[t * H_DIM + c] = f2h(hv - h2f_(hi));
    }
}

// ---------------- residual add + RMSNorm (f32 in) -> res f32, h f32, h f16 ----------------
__global__ __launch_bounds__(256) void add_rms2(const float* __restrict__ a,
                                                const float* __restrict__ b,
                                                const float* __restrict__ w,
                                                float* __restrict__ res,
                                                float* __restrict__ hf,
                                                ushort_t* __restrict__ hh) {
    int t = blockIdx.x, tid = threadIdx.x;
    float v[8];
    float ss = 0.f;
#pragma unroll
    for (int i = 0; i < 8; i++) {
        int idx = t * H_DIM + tid + i * 256;
        v[i] = a[idx] + b[idx];
        res[idx] = v[i];
        ss += v[i] * v[i];
    }
#pragma unroll
    for (int o = 32; o; o >>= 1) ss += __shfl_down(ss, o);
    __shared__ float red[4];
    if ((tid & 63) == 0) red[tid >> 6] = ss;
    __syncthreads();
    float tot = red[0] + red[1] + red[2] + red[3];
    float scale = rsqrtf(tot / (float)H_DIM + EPSF);
#pragma unroll
    for (int i = 0; i < 8; i++) {
        int c = tid + i * 256;
        float hv = v[i] * scale * w[c];
        hf[t * H_DIM + c] = hv;
        hh[t * H_DIM + c] = f2h(hv);
    }
}

// ---------------- cast+transpose f32 [R][C(ld)] -> f16 hi/lo [C][R] ----------------
__global__ __launch_bounds__(256) void castT_hl(const float* __restrict__ in,
                                                ushort_t* __restrict__ oh,
                                                ushort_t* __restrict__ ol,
                                                int R, int ld) {
    __shared__ float tile[32][33];
    int r0 = blockIdx.y * 32, c0 = blockIdx.x * 32;
    int tx = threadIdx.x & 31, ty = threadIdx.x >> 5;
#pragma unroll
    for (int i = 0; i < 4; i++)
        tile[ty + 8 * i][tx] = in[(size_t)(r0 + ty + 8 * i) * ld + c0 + tx];
    __syncthreads();
#pragma unroll
    for (int i = 0; i < 4; i++) {
        float v = tile[tx][ty + 8 * i];
        ushort_t hi = f2h(v);
        size_t idx = (size_t)(c0 + ty + 8 * i) * R + r0 + tx;
        oh[idx] = hi;
        ol[idx] = f2h(v - h2f_(hi));
    }
}

// ---------------- cast+transpose f32 [R][C(ld)] -> f16 [C][R], z-batched ----------------
__global__ __launch_bounds__(256) void castT_h(const float* __restrict__ in,
                                               ushort_t* __restrict__ out,
                                               int R, int ld, size_t zstride) {
    in += (size_t)blockIdx.z * zstride;
    out += (size_t)blockIdx.z * zstride;
    __shared__ float tile[32][33];
    int r0 = blockIdx.y * 32, c0 = blockIdx.x * 32;
    int tx = threadIdx.x & 31, ty = threadIdx.x >> 5;
#pragma unroll
    for (int i = 0; i < 4; i++)
        tile[ty + 8 * i][tx] = in[(size_t)(r0 + ty + 8 * i) * ld + c0 + tx];
    __syncthreads();
#pragma unroll
    for (int i = 0; i < 4; i++)
        out[(size_t)(c0 + ty + 8 * i) * R + r0 + tx] = f2h(tile[tx][ty + 8 * i]);
}

// ------- split-f16 MFMA GEMM: C[M,N] (f32) = (Ah+Al)[M,K] @ (Bh+Bl)[N,K]^T -------
__global__ __launch_bounds__(256) void gemm_f16x3(const ushort_t* __restrict__ Ah,
                                                  const ushort_t* __restrict__ Al_,
                                                  const ushort_t* __restrict__ Bh,
                                                  const ushort_t* __restrict__ Bl_,
                                                  float* __restrict__ C,
                                                  int ldc, int K) {
    __shared__ ushort_t sAh[4096], sAl[4096], sBh[4096], sBl[4096];
    int tid = threadIdx.x, lane = tid & 63, wv = tid >> 6;
    int m0 = blockIdx.y * 128, n0 = blockIdx.x * 128;
    int wm = (wv & 1) * 64, wn = (wv >> 1) * 64;
    int fr = lane & 15, fq = lane >> 4;
    f32x4 acc[4][4];
#pragma unroll
    for (int i = 0; i < 4; i++)
#pragma unroll
        for (int j = 0; j < 4; j++) acc[i][j] = {0.f, 0.f, 0.f, 0.f};

    size_t aoff = (size_t)(m0 + wv * 32 + (lane >> 2)) * K + (lane & 3) * 8;
    size_t boff = (size_t)(n0 + wv * 32 + (lane >> 2)) * K + (lane & 3) * 8;
    const ushort_t* gAh = Ah + aoff;
    const ushort_t* gAl = Al_ + aoff;
    const ushort_t* gBh = Bh + boff;
    const ushort_t* gBl = Bl_ + boff;

    for (int k0 = 0; k0 < K; k0 += 32) {
        gld16(gAh, &sAh[(wv * 32) * 32]);
        gld16(gAh + (size_t)16 * K, &sAh[(wv * 32 + 16) * 32]);
        gld16(gAl, &sAl[(wv * 32) * 32]);
        gld16(gAl + (size_t)16 * K, &sAl[(wv * 32 + 16) * 32]);
        gld16(gBh, &sBh[(wv * 32) * 32]);
        gld16(gBh + (size_t)16 * K, &sBh[(wv * 32 + 16) * 32]);
        gld16(gBl, &sBl[(wv * 32) * 32]);
        gld16(gBl + (size_t)16 * K, &sBl[(wv * 32 + 16) * 32]);
        gAh += 32; gAl += 32; gBh += 32; gBl += 32;
        __syncthreads();
        half8 ah[4], al[4], bh[4], bl[4];
#pragma unroll
        for (int i = 0; i < 4; i++) {
            int off = (wm + i * 16 + fr) * 32 + fq * 8;
            ah[i] = *(const half8*)&sAh[off];
            al[i] = *(const half8*)&sAl[off];
        }
#pragma unroll
        for (int j = 0; j < 4; j++) {
            int off = (wn + j * 16 + fr) * 32 + fq * 8;
            bh[j] = *(const half8*)&sBh[off];
            bl[j] = *(const half8*)&sBl[off];
        }
#pragma unroll
        for (int i = 0; i < 4; i++)
#pragma unroll
            for (int j = 0; j < 4; j++) {
                acc[i][j] = __builtin_amdgcn_mfma_f32_16x16x32_f16(ah[i], bh[j], acc[i][j], 0, 0, 0);
                acc[i][j] = __builtin_amdgcn_mfma_f32_16x16x32_f16(ah[i], bl[j], acc[i][j], 0, 0, 0);
                acc[i][j] = __builtin_amdgcn_mfma_f32_16x16x32_f16(al[i], bh[j], acc[i][j], 0, 0, 0);
            }
        __syncthreads();
    }
#pragma unroll
    for (int i = 0; i < 4; i++)
#pragma unroll
        for (int j = 0; j < 4; j++)
#pragma unroll
            for (int r = 0; r < 4; r++) {
                int row = m0 + wm + i * 16 + fq * 4 + r;
                int col = n0 + wn + j * 16 + fr;
                C[(size_t)row * ldc + col] = acc[i][j][r];
            }
}

// ---------------- grouped f16 MFMA GEMM (MoE): gathered A rows, scattered C rows ----------------
__global__ __launch_bounds__(256) void moe_gemm(const ushort_t* __restrict__ Ab,
                                                const ushort_t* __restrict__ BtAll,
                                                const int* __restrict__ cnt,
                                                const int* __restrict__ ridx_g,
                                                const int* __restrict__ oidx_g,
                                                ushort_t* __restrict__ Cout,
                                                int N, int K, int ebase) {
    int e = ebase + blockIdx.z;
    int nt = cnt[e];
    int mt0 = blockIdx.y * 128;
    if (mt0 >= nt) return;
    const ushort_t* Bt = BtAll + (size_t)blockIdx.z * N * K;
    int n0 = blockIdx.x * 128;
    __shared__ ushort_t Al[4096];
    __shared__ ushort_t Bl[4096];
    __shared__ int ridx[128], oidx[128];
    int tid = threadIdx.x, lane = tid & 63, wv = tid >> 6;
    if (tid < 128) {
        int ii = mt0 + tid;
        bool v = ii < nt;
        ridx[tid] = v ? ridx_g[e * T_TOK + ii] : -1;
        oidx[tid] = v ? oidx_g[e * T_TOK + ii] : -1;
    }
    __syncthreads();
    int wm = (wv & 1) * 64, wn = (wv >> 1) * 64;
    int fr = lane & 15, fq = lane >> 4;
    f32x4 acc[4][4];
#pragma unroll
    for (int i = 0; i < 4; i++)
#pragma unroll
        for (int j = 0; j < 4; j++) acc[i][j] = {0.f, 0.f, 0.f, 0.f};

    int arow = tid >> 1, akoff = (tid & 1) * 16;
    int ra = ridx[arow];
    const ushort_t* asrc = (ra >= 0) ? (Ab + (size_t)ra * K + akoff) : (const ushort_t*)0;
    const ushort_t* gB = Bt + (size_t)(n0 + wv * 32 + (lane >> 2)) * K + (lane & 3) * 8;

    for (int k0 = 0; k0 < K; k0 += 32) {
        uint4 v0 = {0, 0, 0, 0}, v1 = {0, 0, 0, 0};
        if (ra >= 0) {
            v0 = *(const uint4*)(asrc);
            v1 = *(const uint4*)(asrc + 8);
            asrc += 32;
        }
        gld16(gB, &Bl[(wv * 32) * 32]);
        gld16(gB + (size_t)16 * K, &Bl[(wv * 32 + 16) * 32]);
        gB += 32;
        *(uint4*)&Al[arow * 32 + akoff] = v0;
        *(uint4*)&Al[arow * 32 + akoff + 8] = v1;
        __syncthreads();
        half8 af[4], bfr[4];
#pragma unroll
        for (int i = 0; i < 4; i++) af[i] = *(const half8*)&Al[(wm + i * 16 + fr) * 32 + fq * 8];
#pragma unroll
        for (int j = 0; j < 4; j++) bfr[j] = *(const half8*)&Bl[(wn + j * 16 + fr) * 32 + fq * 8];
#pragma unroll
        for (int i = 0; i < 4; i++)
#pragma unroll
            for (int j = 0; j < 4; j++)
                acc[i][j] = __builtin_amdgcn_mfma_f32_16x16x32_f16(af[i], bfr[j], acc[i][j], 0, 0, 0);
        __syncthreads();
    }
#pragma unroll
    for (int i = 0; i < 4; i++)
#pragma unroll
        for (int j = 0; j < 4; j++)
#pragma unroll
            for (int r = 0; r < 4; r++) {
                int lr = wm + i * 16 + fq * 4 + r;
                if (mt0 + lr < nt) {
                    int orow = oidx[lr];
                    Cout[(size_t)orow * N + n0 + wn + j * 16 + fr] = f2h(acc[i][j][r]);
                }
            }
}

// ---------------- QK RMSNorm + neox RoPE (in-place on f32 qkv) ----------------
__global__ __launch_bounds__(128) void qk_rope(float* __restrict__ qkv,
                                               const float* __restrict__ qw,
                                               const float* __restrict__ kw,
                                               const int* __restrict__ positions) {
    int t = blockIdx.x / (NH + NKV);
    int hh = blockIdx.x % (NH + NKV);
    float* x;
    const float* w;
    if (hh < NH) { x = qkv + (size_t)t * 3072 + hh * HD; w = qw; }
    else         { x = qkv + (size_t)t * 3072 + 2048 + (hh - NH) * HD; w = kw; }
    int tid = threadIdx.x;
    float v = x[tid];
    float ss = v * v;
#pragma unroll
    for (int o = 32; o; o >>= 1) ss += __shfl_down(ss, o);
    __shared__ float red[2];
    if ((tid & 63) == 0) red[tid >> 6] = ss;
    __syncthreads();
    float tot = red[0] + red[1];
    float scale = rsqrtf(tot / (float)HD + EPSF);
    float xn = v * scale * w[tid];
    __shared__ float buf[HD];
    buf[tid] = xn;
    __syncthreads();
    if (tid < 64) {
        float x1 = buf[tid], x2 = buf[tid + 64];
        float invf = expf(-((float)tid / 64.0f) * logf(1000000.0f));
        float ang = (float)positions[t] * invf;
        float c = cosf(ang), s = sinf(ang);
        x[tid] = x1 * c - x2 * s;
        x[tid + 64] = x2 * c + x1 * s;
    }
}

// ---------------- MFMA flash attention: f16 hi/lo split (3-MFMA), f32 softmax ----------------
// block = 256 threads (4 waves), one block per (head, 64-query tile).
// wave w owns q-rows [w*16, w*16+16). S tile 64x64 per k-step via 16x16x32 f16 MFMA.
#define ATT_SCALE 0.08838834764831845f
__global__ __launch_bounds__(256) void attn_mfma(const float* __restrict__ qkv,
                                                 ushort_t* __restrict__ ohp,
                                                 ushort_t* __restrict__ olp) {
    // padded strides: 136 halves (K rows), 72 halves (Vt/P rows) -> 2-way max bank aliasing
    __shared__ _Float16 sKh[64 * 136], sKl[64 * 136];
    __shared__ _Float16 sVh[128 * 72], sVl[128 * 72];
    __shared__ _Float16 sQh[64 * 136], sQl[64 * 136];  // reused as Ph/Pl [64][72] after preload

    int qi = blockIdx.x, h = blockIdx.y;
    int q0 = qi * 64, g = h >> 2;
    int tid = threadIdx.x, lane = tid & 63, wv = tid >> 6;
    int quad = lane >> 4, n16 = lane & 15;

    // ---- stage Q tile (hi/lo f16), row-major padded ----
    {
        int r = tid >> 2, c0 = (tid & 3) * 32;
        const float* qp = qkv + (size_t)(q0 + r) * 3072 + h * HD + c0;
#pragma unroll
        for (int i = 0; i < 8; i++) {
            float4 v = *(const float4*)(qp + i * 4);
            float vv[4] = {v.x, v.y, v.z, v.w};
            us4 h4, l4;
#pragma unroll
            for (int p = 0; p < 4; p++) {
                _Float16 hi = (_Float16)vv[p];
                h4[p] = __builtin_bit_cast(ushort_t, hi);
                l4[p] = __builtin_bit_cast(ushort_t, (_Float16)(vv[p] - (float)hi));
            }
            *(us4*)&sQh[r * 136 + c0 + i * 4] = h4;
            *(us4*)&sQl[r * 136 + c0 + i * 4] = l4;
        }
    }
    __syncthreads();
    // ---- preload Q A-frags: A[m=lane&15][k=quad*8+j], k-step 32 ----
    half8 qh[4], ql[4];
#pragma unroll
    for (int ks = 0; ks < 4; ks++) {
        int off = (wv * 16 + n16) * 136 + ks * 32 + quad * 8;
        qh[ks] = *(const half8*)&sQh[off];
        ql[ks] = *(const half8*)&sQl[off];
    }
    _Float16* sPh = sQh;  // [64][72]
    _Float16* sPl = sQl;

    float m_r[4], l_r[4];
#pragma unroll
    for (int r = 0; r < 4; r++) { m_r[r] = -1e30f; l_r[r] = 0.f; }
    f32x4 acc[8];
#pragma unroll
    for (int d = 0; d < 8; d++) acc[d] = {0.f, 0.f, 0.f, 0.f};

    for (int kt = 0; kt <= qi; kt++) {
        __syncthreads();  // previous tile fully consumed
        // ---- stage K row-major + V transposed (hi/lo f16) ----
        {
            int r = tid >> 2, c0 = (tid & 3) * 32;
            const float* kp = qkv + (size_t)(kt * 64 + r) * 3072 + 2048 + g * HD + c0;
#pragma unroll
            for (int i = 0; i < 8; i++) {
                float4 v = *(const float4*)(kp + i * 4);
                float vv[4] = {v.x, v.y, v.z, v.w};
                us4 h4, l4;
#pragma unroll
                for (int p = 0; p < 4; p++) {
                    _Float16 hi = (_Float16)vv[p];
                    h4[p] = __builtin_bit_cast(ushort_t, hi);
                    l4[p] = __builtin_bit_cast(ushort_t, (_Float16)(vv[p] - (float)hi));
                }
                *(us4*)&sKh[r * 136 + c0 + i * 4] = h4;
                *(us4*)&sKl[r * 136 + c0 + i * 4] = l4;
            }
            int cv0 = (tid & 3) * 4;
            const float* vp = qkv + (size_t)(kt * 64 + r) * 3072 + 2560 + g * HD + cv0;
#pragma unroll
            for (int i = 0; i < 8; i++) {
                float4 v = *(const float4*)(vp + i * 16);
                float vv[4] = {v.x, v.y, v.z, v.w};
#pragma unroll
                for (int p = 0; p < 4; p++) {
                    int d = cv0 + i * 16 + p;
                    _Float16 hi = (_Float16)vv[p];
                    sVh[d * 72 + r] = hi;
                    sVl[d * 72 + r] = (_Float16)(vv[p] - (float)hi);
                }
            }
        }
        __syncthreads();

        // ---- S = Q K^T : per wave 16q x 64k, hi*hi + hi*lo + lo*hi ----
        f32x4 s[4];
#pragma unroll
        for (int jt = 0; jt < 4; jt++) s[jt] = {0.f, 0.f, 0.f, 0.f};
#pragma unroll
        for (int ks = 0; ks < 4; ks++)
#pragma unroll
            for (int jt = 0; jt < 4; jt++) {
                int off = (jt * 16 + n16) * 136 + ks * 32 + quad * 8;
                half8 bh = *(const half8*)&sKh[off];
                half8 bl = *(const half8*)&sKl[off];
                s[jt] = __builtin_amdgcn_mfma_f32_16x16x32_f16(qh[ks], bh, s[jt], 0, 0, 0);
                s[jt] = __builtin_amdgcn_mfma_f32_16x16x32_f16(qh[ks], bl, s[jt], 0, 0, 0);
                s[jt] = __builtin_amdgcn_mfma_f32_16x16x32_f16(ql[ks], bh, s[jt], 0, 0, 0);
            }

        // ---- online softmax in C-layout (row = quad*4+r, col = jt*16+n16) ----
        bool last = (kt == qi);
        int lrow_base = wv * 16 + quad * 4;
#pragma unroll
        for (int r = 0; r < 4; r++) {
            float rm = -1e30f;
#pragma unroll
            for (int jt = 0; jt < 4; jt++) {
                float sv = s[jt][r] * ATT_SCALE;
                if (last && (jt * 16 + n16 > lrow_base + r)) sv = -1e30f;
                s[jt][r] = sv;
                rm = fmaxf(rm, sv);
            }
            rm = fmaxf(rm, __shfl_xor(rm, 1));
            rm = fmaxf(rm, __shfl_xor(rm, 2));
            rm = fmaxf(rm, __shfl_xor(rm, 4));
            rm = fmaxf(rm, __shfl_xor(rm, 8));
            float mo = m_r[r], mn = fmaxf(mo, rm);
            float al = __expf(mo - mn);
            float ls = 0.f;
#pragma unroll
            for (int jt = 0; jt < 4; jt++) {
                float p = __expf(s[jt][r] - mn);
                ls += p;
                _Float16 phi = (_Float16)p;
                int poff = (lrow_base + r) * 72 + jt * 16 + n16;
                sPh[poff] = phi;
                sPl[poff] = (_Float16)(p - (float)phi);
            }
            ls += __shfl_xor(ls, 1);
            ls += __shfl_xor(ls, 2);
            ls += __shfl_xor(ls, 4);
            ls += __shfl_xor(ls, 8);
            l_r[r] = l_r[r] * al + ls;
            m_r[r] = mn;
#pragma unroll
            for (int dt = 0; dt < 8; dt++) acc[dt][r] *= al;
        }
        __syncthreads();  // P visible (also orders same-wave LDS write->read)

        // ---- PV: P (A-layout via LDS round-trip) x V (B from transposed Vt) ----
        half8 pah[2], pal[2];
#pragma unroll
        for (int ks = 0; ks < 2; ks++) {
            int off = (wv * 16 + n16) * 72 + ks * 32 + quad * 8;
            pah[ks] = *(const half8*)&sPh[off];
            pal[ks] = *(const half8*)&sPl[off];
        }
#pragma unroll
        for (int dt = 0; dt < 8; dt++)
#pragma unroll
            for (int ks = 0; ks < 2; ks++) {
                int off = (dt * 16 + n16) * 72 + ks * 32 + quad * 8;
                half8 vh = *(const half8*)&sVh[off];
                half8 vl = *(const half8*)&sVl[off];
                acc[dt] = __builtin_amdgcn_mfma_f32_16x16x32_f16(pah[ks], vh, acc[dt], 0, 0, 0);
                acc[dt] = __builtin_amdgcn_mfma_f32_16x16x32_f16(pah[ks], vl, acc[dt], 0, 0, 0);
                acc[dt] = __builtin_amdgcn_mfma_f32_16x16x32_f16(pal[ks], vh, acc[dt], 0, 0, 0);
            }
    }

    // ---- epilogue: o = acc / l, written as f16 hi/lo planes ----
#pragma unroll
    for (int r = 0; r < 4; r++) {
        float inv = 1.f / l_r[r];
        int row = q0 + wv * 16 + quad * 4 + r;
#pragma unroll
        for (int dt = 0; dt < 8; dt++) {
            float val = acc[dt][r] * inv;
            _Float16 hi = (_Float16)val;
            size_t idx = (size_t)row * 2048 + h * HD + dt * 16 + n16;
            ohp[idx] = __builtin_bit_cast(ushort_t, hi);
            olp[idx] = __builtin_bit_cast(ushort_t, (_Float16)(val - (float)hi));
        }
    }
}

// ---------------- router: softmax over 8 experts, top-2, bucket by expert ----------------
__global__ __launch_bounds__(256) void router(const float* __restrict__ h2,
                                              const float* __restrict__ gate_w,
                                              int* __restrict__ cnt,
                                              int* __restrict__ btok,
                                              int* __restrict__ bslot,
                                              float* __restrict__ wslot) {
    int t = blockIdx.x, tid = threadIdx.x;
    int e = tid & 7, c = tid >> 3;
    float part = 0.f;
    for (int i = 0; i < 64; i++) {
        int hh = c * 64 + i;
        part += h2[(size_t)t * H_DIM + hh] * gate_w[hh * NEXP + e];
    }
    __shared__ float red[256];
    red[tid] = part;
    __syncthreads();
    for (int s = 128; s >= 8; s >>= 1) {
        if (tid < s) red[tid] += red[tid + s];
        __syncthreads();
    }
    if (tid == 0) {
        float mx = -1e30f;
        for (int i = 0; i < NEXP; i++) mx = fmaxf(mx, red[i]);
        float p[NEXP];
        for (int i = 0; i < NEXP; i++) p[i] = expf(red[i] - mx);
        int i1 = 0;
        for (int i = 1; i < NEXP; i++) if (p[i] > p[i1]) i1 = i;
        int i2 = (i1 == 0) ? 1 : 0;
        for (int i = 0; i < NEXP; i++) if (i != i1 && p[i] > p[i2]) i2 = i;
        float denom = p[i1] + p[i2];
        wslot[2 * t] = p[i1] / denom;
        wslot[2 * t + 1] = p[i2] / denom;
        int pos = atomicAdd(&cnt[i1], 1);
        btok[i1 * T_TOK + pos] = t; bslot[i1 * T_TOK + pos] = 2 * t;
        pos = atomicAdd(&cnt[i2], 1);
        btok[i2 * T_TOK + pos] = t; bslot[i2 * T_TOK + pos] = 2 * t + 1;
    }
}

// ---------------- SwiGLU: gu f16 [2048][1536] -> act f16 [2048][768] ----------------
__global__ __launch_bounds__(256) void swiglu(const ushort_t* __restrict__ gu,
                                              ushort_t* __restrict__ act) {
    int idx = blockIdx.x * 256 + threadIdx.x;
    int s = idx / I_DIM, i = idx - s * I_DIM;
    float g = h2f_(gu[(size_t)s * (2 * I_DIM) + i]);
    float u = h2f_(gu[(size_t)s * (2 * I_DIM) + I_DIM + i]);
    act[idx] = f2h(g / (1.f + expf(-g)) * u);
}

// ---------------- combine: out[t] = w0*dbuf[2t] + w1*dbuf[2t+1] ----------------
__global__ __launch_bounds__(256) void combine(const ushort_t* __restrict__ dbuf,
                                               const float* __restrict__ wslot,
                                               float* __restrict__ out) {
    int idx = blockIdx.x * 256 + threadIdx.x;
    int t = idx >> 11;
    out[idx] = wslot[2 * t] * h2f_(dbuf[(size_t)(2 * t) * H_DIM + (idx & 2047)]) +
               wslot[2 * t + 1] * h2f_(dbuf[(size_t)(2 * t + 1) * H_DIM + (idx & 2047)]);
}

extern "C" void kernel_launch(void* const* d_in, const int* in_sizes, int n_in,
                              void* d_out, int out_size, void* d_ws, size_t ws_size,
                              hipStream_t stream) {
    const int* positions = (const int*)d_in[0];
    const float* hs = (const float*)d_in[1];
    const float* resid = (const float*)d_in[2];
    const float* w_qkv = (const float*)d_in[3];
    const float* w_o = (const float*)d_in[4];
    const float* q_norm_w = (const float*)d_in[5];
    const float* k_norm_w = (const float*)d_in[6];
    const float* ln1_w = (const float*)d_in[7];
    const float* ln2_w = (const float*)d_in[8];
    const float* gate_w = (const float*)d_in[9];
    const float* w_gu = (const float*)d_in[10];
    const float* w_dn = (const float*)d_in[11];

    float* out = (float*)d_out;
    float* res2 = out + (size_t)T_TOK * H_DIM;

    const size_t MB = 1ull << 20;
    char* W = (char*)d_ws;
    // region A: 0-8 MiB
    float*    res1   = (float*)(W + 0);          // live steps 2-8
    ushort_t* dbuf   = (ushort_t*)(W + 0);       // f16 [2048][2048], live 12-13
    // region B: 8-16 MiB
    ushort_t* h1h    = (ushort_t*)(W + 8 * MB);  // live 2-3
    ushort_t* h1l    = (ushort_t*)(W + 12 * MB);
    ushort_t* ohp    = (ushort_t*)(W + 8 * MB);  // live 6-7
    ushort_t* olp    = (ushort_t*)(W + 12 * MB);
    ushort_t* h2h    = (ushort_t*)(W + 8 * MB);  // live 8-12
    ushort_t* actb   = (ushort_t*)(W + 12 * MB); // 3 MiB, live 11-12
    // region C: 16-28 MiB
    float*    qkvf   = (float*)(W + 16 * MB);    // 12 MiB, live 3-6
    float*    oprojf = (float*)(W + 16 * MB);    // 8 MiB, live 7-8
    ushort_t* gub    = (ushort_t*)(W + 16 * MB); // 6 MiB, live 10-11
    // region D: 28-44 MiB (weight transposes)
    ushort_t* wTh    = (ushort_t*)(W + 28 * MB); // qkv chunk hi 6 MiB / w_o hi 8 MiB / moe 12 MiB
    ushort_t* wTl_q  = (ushort_t*)(W + 34 * MB); // qkv chunk lo 6 MiB
    ushort_t* wTl_o  = (ushort_t*)(W + 36 * MB); // w_o lo 8 MiB (28-36 hi, 36-44 lo)
    // region E: 40-48 MiB
    float*    h2f    = (float*)(W + 40 * MB);    // 8 MiB, live 8-9
    // buckets: 48 MiB+
    int*      cnt    = (int*)(W + 48 * MB);
    int*      btok   = cnt + 16;
    int*      bslot  = btok + NEXP * T_TOK;
    float*    wslot  = (float*)(bslot + NEXP * T_TOK);

    // 1+2. res1 = hs + resid; h1 = rms(res1)*ln1 as f16 hi/lo
    add_rms1<<<T_TOK, 256, 0, stream>>>(hs, resid, ln1_w, res1, h1h, h1l);
    // 3. qkv = h1 @ w_qkv in two N-chunks of 1536 (f16x3 split GEMM, f32 out)
    for (int c = 0; c < 2; c++) {
        castT_hl<<<dim3(1536 / 32, 2048 / 32), 256, 0, stream>>>(
            w_qkv + c * 1536, wTh, wTl_q, 2048, 3072);
        gemm_f16x3<<<dim3(1536 / 128, 1024 / 128), 256, 0, stream>>>(
            h1h, h1l, wTh, wTl_q, qkvf + c * 1536, 3072, 2048);
    }
    // 4. q/k RMSNorm + RoPE in place (f32)
    qk_rope<<<T_TOK * (NH + NKV), 128, 0, stream>>>(qkvf, q_norm_w, k_norm_w, positions);
    // 5. w_o transpose hi/lo
    castT_hl<<<dim3(2048 / 32, 2048 / 32), 256, 0, stream>>>(w_o, wTh, wTl_o, 2048, 2048);
    // 6. MFMA flash attention -> o hi/lo f16 planes
    attn_mfma<<<dim3(T_TOK / 64, NH), 256, 0, stream>>>(qkvf, ohp, olp);
    // 7. oproj = attn_out @ w_o (f16x3, f32 out)
    gemm_f16x3<<<dim3(2048 / 128, 1024 / 128), 256, 0, stream>>>(
        ohp, olp, wTh, wTl_o, oprojf, 2048, 2048);
    // 8. res2 = oproj + res1 (-> d_out); h2 f32 + f16
    add_rms2<<<T_TOK, 256, 0, stream>>>(oprojf, res1, ln2_w, res2, h2f, h2h);
    // 9. router (f32 logits)
    hipMemsetAsync(cnt, 0, NEXP * sizeof(int), stream);
    router<<<T_TOK, 256, 0, stream>>>(h2f, gate_w, cnt, btok, bslot, wslot);
    // 10. MoE gate_up in 4 chunks of 2 experts
    for (int c = 0; c < 4; c++) {
        castT_h<<<dim3(1536 / 32, 2048 / 32, 2), 256, 0, stream>>>(
            w_gu + (size_t)c * 2 * 2048 * 1536, wTh, 2048, 1536, (size_t)2048 * 1536);
        moe_gemm<<<dim3(1536 / 128, 8, 2), 256, 0, stream>>>(
            h2h, wTh, cnt, btok, bslot, gub, 1536, 2048, c * 2);
    }
    // 11. SwiGLU
    swiglu<<<(2048 * I_DIM) / 256, 256, 0, stream>>>(gub, actb);
    // 12. MoE down in 2 chunks of 4 experts
    for (int c = 0; c < 2; c++) {
        castT_h<<<dim3(2048 / 32, 768 / 32, 4), 256, 0, stream>>>(
            w_dn + (size_t)c * 4 * 768 * 2048, wTh, 768, 2048, (size_t)768 * 2048);
        moe_gemm<<<dim3(2048 / 128, 8, 4), 256, 0, stream>>>(
            actb, wTh, cnt, bslot, bslot, dbuf, 2048, 768, c * 4);
    }
    // 13. weighted combine
    combine<<<(T_TOK * H_DIM) / 256, 256, 0, stream>>>(dbuf, wslot, out);
}